// Round 2
// baseline (340.966 us; speedup 1.0000x reference)
//
#include <hip/hip_runtime.h>
#include <math.h>

// Problem constants: B=2, L=1024, D=512, H=8, h=64, K=H=8, EPS=1e-5
// Layouts: q/k/v/k_conv/v_conv stored as [B*H][L][64] (bh*65536 + l*64 + d)

// ---------------------------------------------------------------------------
// K1: fused QKV projection.  x[2048,512] @ W[512,512] (+bias)*scale, written
// into [B,H,L,h] layout.  grid (8 colTiles, 32 rowTiles, 3 weights), 256 thr.
// ---------------------------------------------------------------------------
__global__ __launch_bounds__(256) void k_qkv(
    const float* __restrict__ x,
    const float* __restrict__ wq, const float* __restrict__ bq,
    const float* __restrict__ wk, const float* __restrict__ bk,
    const float* __restrict__ wv, const float* __restrict__ bv,
    float* __restrict__ qo, float* __restrict__ ko, float* __restrict__ vo)
{
    const int tid = threadIdx.x;
    const int tx = tid & 15, ty = tid >> 4;
    const int col0 = blockIdx.x * 64;   // head = blockIdx.x (64 cols per head)
    const int row0 = blockIdx.y * 64;
    const float* w; const float* bias; float* dst; float scale;
    if (blockIdx.z == 0)      { w = wq; bias = bq; dst = qo; scale = 1.0f;   }
    else if (blockIdx.z == 1) { w = wk; bias = bk; dst = ko; scale = 0.125f; } // h^-0.5
    else                      { w = wv; bias = bv; dst = vo; scale = 1.0f;   }

    __shared__ float xs[64][17];
    __shared__ __align__(16) float wsb[16][68];
    float acc[4][4] = {};

    const float4* x4 = (const float4*)x;
    const float4* w4 = (const float4*)w;
    for (int k0 = 0; k0 < 512; k0 += 16) {
        {   // load x tile 64x16
            int r = tid >> 2, c4 = tid & 3;
            float4 t = x4[(size_t)(row0 + r) * 128 + (k0 >> 2) + c4];
            xs[r][c4*4+0] = t.x; xs[r][c4*4+1] = t.y;
            xs[r][c4*4+2] = t.z; xs[r][c4*4+3] = t.w;
        }
        {   // load w tile 16x64
            int r = tid >> 4, c4 = tid & 15;
            float4 t = w4[(size_t)(k0 + r) * 128 + (col0 >> 2) + c4];
            *(float4*)&wsb[r][c4*4] = t;
        }
        __syncthreads();
        #pragma unroll
        for (int kk = 0; kk < 16; ++kk) {
            float a[4];
            a[0] = xs[ty*4+0][kk]; a[1] = xs[ty*4+1][kk];
            a[2] = xs[ty*4+2][kk]; a[3] = xs[ty*4+3][kk];
            float4 b4 = *(const float4*)&wsb[kk][tx*4];
            float bb[4] = {b4.x, b4.y, b4.z, b4.w};
            #pragma unroll
            for (int ii = 0; ii < 4; ++ii)
                #pragma unroll
                for (int jj = 0; jj < 4; ++jj)
                    acc[ii][jj] += a[ii] * bb[jj];
        }
        __syncthreads();
    }

    const int b  = row0 >> 10;
    const int hd = blockIdx.x;
    const int dd = tx * 4;
    #pragma unroll
    for (int i = 0; i < 4; ++i) {
        int l = (row0 & 1023) + ty*4 + i;
        float4 o;
        o.x = (acc[i][0] + bias[col0+dd+0]) * scale;
        o.y = (acc[i][1] + bias[col0+dd+1]) * scale;
        o.z = (acc[i][2] + bias[col0+dd+2]) * scale;
        o.w = (acc[i][3] + bias[col0+dd+3]) * scale;
        *(float4*)&dst[(size_t)((b*8 + hd)*1024 + l) * 64 + dd] = o;
    }
}

// ---------------------------------------------------------------------------
// K2: causal Toeplitz conv, split-s.  y[t,d] = sum_{s<=t} f[t-s]*u[s,d].
// grid (16 tTiles, 8 sChunks of 128, 32 = tensor*16 + bh), 256 thr.
// Each active block accumulates its s-chunk's partial into KC/VC via
// atomicAdd (targets memset to zero before launch).  <=8 inner iterations
// per block -> balanced; 2304 active blocks -> high occupancy.
// ---------------------------------------------------------------------------
__global__ __launch_bounds__(256) void k_conv(
    const float* __restrict__ sb,
    const float* __restrict__ kin, const float* __restrict__ vin,
    float* __restrict__ kc, float* __restrict__ vc)
{
    const int tid = threadIdx.x, tx = tid & 15, ty = tid >> 4;
    const int t0  = blockIdx.x * 64;
    const int sc  = blockIdx.y;
    const int tns = blockIdx.z >> 4;
    const int bh  = blockIdx.z & 15;
    const int hd  = bh & 7;
    const int sbeg = sc * 128;
    if (sbeg >= t0 + 64) return;          // block-uniform early exit
    const int send = min(sbeg + 128, t0 + 64);

    const float* src = (tns ? vin : kin) + (size_t)bh * 65536;
    float*       dst = (tns ? vc  : kc ) + (size_t)bh * 65536;

    __shared__ __align__(16) float us[16][68];
    __shared__ float fwin[80];
    float acc[4][4] = {};

    const float4* s4 = (const float4*)src;
    for (int s0 = sbeg; s0 < send; s0 += 16) {
        const int base = t0 - s0 - 15;
        if (tid < 80) {
            int idx = base + tid;
            fwin[tid] = (idx >= 0 && idx < 1024) ? sb[idx*8 + hd] : 0.0f;
        }
        {
            int r = tid >> 4, c4 = tid & 15;
            float4 t = s4[(size_t)(s0 + r) * 16 + c4];
            *(float4*)&us[r][c4*4] = t;
        }
        __syncthreads();
        #pragma unroll
        for (int kk = 0; kk < 16; ++kk) {
            // f[t-s] with t = t0+ty*4+i, s = s0+kk -> fwin[(ty*4+i) + 15 - kk]
            float f[4];
            f[0] = fwin[ty*4+0 + 15 - kk];
            f[1] = fwin[ty*4+1 + 15 - kk];
            f[2] = fwin[ty*4+2 + 15 - kk];
            f[3] = fwin[ty*4+3 + 15 - kk];
            float4 u4 = *(const float4*)&us[kk][tx*4];
            float uu[4] = {u4.x, u4.y, u4.z, u4.w};
            #pragma unroll
            for (int ii = 0; ii < 4; ++ii)
                #pragma unroll
                for (int jj = 0; jj < 4; ++jj)
                    acc[ii][jj] += f[ii] * uu[jj];
        }
        __syncthreads();
    }
    #pragma unroll
    for (int i = 0; i < 4; ++i) {
        float* row = &dst[(size_t)(t0 + ty*4 + i) * 64 + tx*4];
        atomicAdd(row + 0, acc[i][0]);
        atomicAdd(row + 1, acc[i][1]);
        atomicAdd(row + 2, acc[i][2]);
        atomicAdd(row + 3, acc[i][3]);
    }
}

// ---------------------------------------------------------------------------
// K3: gate values.  T = K_conv @ Wg^T (T[l,m] = sum_n k[l,n]*wg[m*64+n]),
// logit[l] = sum_m v[l,m]*T[l,m] + wg_b; g = relu(logit)^2 + EPS.
// grid (16 lTiles, 16 bh), 256 thr.
// ---------------------------------------------------------------------------
__global__ __launch_bounds__(256) void k_gate(
    const float* __restrict__ kc, const float* __restrict__ vc,
    const float* __restrict__ wg_w, const float* __restrict__ wg_b,
    float* __restrict__ gl)
{
    const int tid = threadIdx.x, tx = tid & 15, ty = tid >> 4;
    const int l0 = blockIdx.x * 64;
    const int bh = blockIdx.y;
    const float* kb = kc + (size_t)bh * 65536;
    const float* vb = vc + (size_t)bh * 65536;

    __shared__ float ks[64][17];
    __shared__ __align__(16) float wsh[16][68];
    float acc[4][4] = {};
    const float4* k4 = (const float4*)kb;
    for (int n0 = 0; n0 < 64; n0 += 16) {
        {
            int r = tid >> 2, c4 = tid & 3;
            float4 t = k4[(size_t)(l0 + r) * 16 + (n0 >> 2) + c4];
            ks[r][c4*4+0]=t.x; ks[r][c4*4+1]=t.y; ks[r][c4*4+2]=t.z; ks[r][c4*4+3]=t.w;
        }
        for (int i = tid; i < 1024; i += 256) {   // wsh[nn][m] = wg[m*64 + n0+nn]
            int r = i >> 6, c = i & 63;
            wsh[r][c] = wg_w[c*64 + n0 + r];
        }
        __syncthreads();
        #pragma unroll
        for (int kk = 0; kk < 16; ++kk) {
            float a[4];
            a[0] = ks[ty*4+0][kk]; a[1] = ks[ty*4+1][kk];
            a[2] = ks[ty*4+2][kk]; a[3] = ks[ty*4+3][kk];
            float4 b4 = *(const float4*)&wsh[kk][tx*4];
            float bb[4] = {b4.x, b4.y, b4.z, b4.w};
            #pragma unroll
            for (int ii = 0; ii < 4; ++ii)
                #pragma unroll
                for (int jj = 0; jj < 4; ++jj)
                    acc[ii][jj] += a[ii] * bb[jj];
        }
        __syncthreads();
    }
    __shared__ float red[64][17];
    const float wgb = wg_b[0];
    const float4* v4p = (const float4*)vb;
    #pragma unroll
    for (int i = 0; i < 4; ++i) {
        int lr = ty*4 + i;
        float4 vv = v4p[(size_t)(l0 + lr) * 16 + tx];
        red[lr][tx] = acc[i][0]*vv.x + acc[i][1]*vv.y + acc[i][2]*vv.z + acc[i][3]*vv.w;
    }
    __syncthreads();
    if (tid < 64) {
        float s = 0.0f;
        #pragma unroll
        for (int t = 0; t < 16; ++t) s += red[tid][t];
        float logit = s + wgb;
        float r = fmaxf(logit, 0.0f);
        gl[bh*1024 + l0 + tid] = r*r + 1e-5f;
    }
}

// ---------------------------------------------------------------------------
// K4: scans.  G_l = prefix(g), r_l = 1/(G_l+EPS), c_j = suffix(r),
// w_j = g_j * c_j.  One block per bh, 256 thr x 4 elems.
// ---------------------------------------------------------------------------
__global__ __launch_bounds__(256) void k_scan(
    const float* __restrict__ gl, float* __restrict__ wgt)
{
    const int tid = threadIdx.x, bh = blockIdx.x;
    __shared__ float sbuf[256];
    const float4 g4 = ((const float4*)(gl + bh*1024))[tid];
    float g[4] = {g4.x, g4.y, g4.z, g4.w};
    float p[4];
    p[0]=g[0]; p[1]=p[0]+g[1]; p[2]=p[1]+g[2]; p[3]=p[2]+g[3];
    const float s = p[3];
    sbuf[tid] = s;
    __syncthreads();
    for (int off = 1; off < 256; off <<= 1) {
        float t = (tid >= off) ? sbuf[tid-off] : 0.0f;
        __syncthreads();
        sbuf[tid] += t;
        __syncthreads();
    }
    const float base = sbuf[tid] - s;     // exclusive prefix of g-partials
    float r[4], pr[4];
    #pragma unroll
    for (int u = 0; u < 4; ++u) r[u] = 1.0f / (base + p[u] + 1e-5f);
    pr[0]=r[0]; pr[1]=pr[0]+r[1]; pr[2]=pr[1]+r[2]; pr[3]=pr[2]+r[3];
    const float sr = pr[3];
    __syncthreads();
    sbuf[tid] = sr;
    __syncthreads();
    for (int off = 1; off < 256; off <<= 1) {
        float t = (tid >= off) ? sbuf[tid-off] : 0.0f;
        __syncthreads();
        sbuf[tid] += t;
        __syncthreads();
    }
    const float Rtot  = sbuf[255];
    const float baser = sbuf[tid] - sr;
    float4 o;
    o.x = g[0] * (Rtot - (baser + pr[0]) + r[0]);
    o.y = g[1] * (Rtot - (baser + pr[1]) + r[1]);
    o.z = g[2] * (Rtot - (baser + pr[2]) + r[2]);
    o.w = g[3] * (Rtot - (baser + pr[3]) + r[3]);
    ((float4*)(wgt + bh*1024))[tid] = o;
}

// ---------------------------------------------------------------------------
// K5: A_part[slc][bh] = sum_{j in slice} w_j * outer(v_conv[j], k_conv[j]).
// grid (16 bh, 4 slices), 256 thr, 64x64 output per block.
// ---------------------------------------------------------------------------
__global__ __launch_bounds__(256) void k_amat(
    const float* __restrict__ kc, const float* __restrict__ vc,
    const float* __restrict__ wgt, float* __restrict__ apart)
{
    const int tid = threadIdx.x, tx = tid & 15, ty = tid >> 4;
    const int bh = blockIdx.x, slc = blockIdx.y;
    const float* kb = kc + (size_t)bh * 65536;
    const float* vb = vc + (size_t)bh * 65536;
    const float* wb = wgt + bh*1024;

    __shared__ __align__(16) float vs[16][68];
    __shared__ __align__(16) float ks2[16][68];
    __shared__ float ww[16];
    float acc[4][4] = {};
    const float4* k4 = (const float4*)kb;
    const float4* v4 = (const float4*)vb;
    for (int j0 = slc*256; j0 < slc*256 + 256; j0 += 16) {
        if (tid < 16) ww[tid] = wb[j0 + tid];
        {
            int r = tid >> 4, c4 = tid & 15;
            *(float4*)&vs[r][c4*4]  = v4[(size_t)(j0 + r)*16 + c4];
            *(float4*)&ks2[r][c4*4] = k4[(size_t)(j0 + r)*16 + c4];
        }
        __syncthreads();
        #pragma unroll
        for (int jj = 0; jj < 16; ++jj) {
            float wj = ww[jj];
            float a[4];
            a[0] = vs[jj][ty*4+0]*wj; a[1] = vs[jj][ty*4+1]*wj;
            a[2] = vs[jj][ty*4+2]*wj; a[3] = vs[jj][ty*4+3]*wj;
            float4 b4 = *(const float4*)&ks2[jj][tx*4];
            float bb[4] = {b4.x, b4.y, b4.z, b4.w};
            #pragma unroll
            for (int ii = 0; ii < 4; ++ii)
                #pragma unroll
                for (int jc = 0; jc < 4; ++jc)
                    acc[ii][jc] += a[ii] * bb[jc];
        }
        __syncthreads();
    }
    float* ap = apart + (size_t)(slc*16 + bh) * 4096;
    #pragma unroll
    for (int i = 0; i < 4; ++i) {
        float4 o = { acc[i][0], acc[i][1], acc[i][2], acc[i][3] };
        *(float4*)&ap[(ty*4+i)*64 + tx*4] = o;
    }
}

// ---------------------------------------------------------------------------
// K6: ctxt = q @ A (summing the 4 A-partials on load), row-normalize,
// write unit vectors into [B,L,D] layout.  grid (16 lTiles, 16 bh), 256 thr.
// ---------------------------------------------------------------------------
__global__ __launch_bounds__(256) void k_ctxt(
    const float* __restrict__ q, const float* __restrict__ apart,
    float* __restrict__ u)
{
    const int tid = threadIdx.x, tx = tid & 15, ty = tid >> 4;
    const int l0 = blockIdx.x * 64;
    const int bh = blockIdx.y;
    const float* qb = q + (size_t)bh * 65536;

    __shared__ float qs[64][17];
    __shared__ __align__(16) float As[16][68];
    float acc[4][4] = {};
    const float4* q4 = (const float4*)qb;
    const float4* a4 = (const float4*)apart;
    for (int d0 = 0; d0 < 64; d0 += 16) {
        {
            int r = tid >> 2, c4 = tid & 3;
            float4 t = q4[(size_t)(l0 + r)*16 + (d0 >> 2) + c4];
            qs[r][c4*4+0]=t.x; qs[r][c4*4+1]=t.y; qs[r][c4*4+2]=t.z; qs[r][c4*4+3]=t.w;
        }
        {
            int r = tid >> 4, c4 = tid & 15;
            size_t o = (size_t)(d0 + r)*16 + c4;
            float4 t0 = a4[(size_t)(0*16 + bh)*1024 + o];
            float4 t1 = a4[(size_t)(1*16 + bh)*1024 + o];
            float4 t2 = a4[(size_t)(2*16 + bh)*1024 + o];
            float4 t3 = a4[(size_t)(3*16 + bh)*1024 + o];
            float4 t;
            t.x = t0.x+t1.x+t2.x+t3.x; t.y = t0.y+t1.y+t2.y+t3.y;
            t.z = t0.z+t1.z+t2.z+t3.z; t.w = t0.w+t1.w+t2.w+t3.w;
            *(float4*)&As[r][c4*4] = t;
        }
        __syncthreads();
        #pragma unroll
        for (int dd = 0; dd < 16; ++dd) {
            float a[4];
            a[0] = qs[ty*4+0][dd]; a[1] = qs[ty*4+1][dd];
            a[2] = qs[ty*4+2][dd]; a[3] = qs[ty*4+3][dd];
            float4 b4 = *(const float4*)&As[dd][tx*4];
            float bb[4] = {b4.x, b4.y, b4.z, b4.w};
            #pragma unroll
            for (int ii = 0; ii < 4; ++ii)
                #pragma unroll
                for (int jj = 0; jj < 4; ++jj)
                    acc[ii][jj] += a[ii] * bb[jj];
        }
        __syncthreads();
    }
    __shared__ float red[64][17];
    __shared__ float nrm[64];
    #pragma unroll
    for (int i = 0; i < 4; ++i) {
        red[ty*4+i][tx] = acc[i][0]*acc[i][0] + acc[i][1]*acc[i][1]
                        + acc[i][2]*acc[i][2] + acc[i][3]*acc[i][3];
    }
    __syncthreads();
    if (tid < 64) {
        float s = 0.0f;
        #pragma unroll
        for (int t = 0; t < 16; ++t) s += red[tid][t];
        nrm[tid] = fmaxf(sqrtf(s), 1e-5f);
    }
    __syncthreads();
    const int b = bh >> 3, hd = bh & 7;
    #pragma unroll
    for (int i = 0; i < 4; ++i) {
        int lr = ty*4 + i;
        float inv = 1.0f / nrm[lr];
        float4 o = { acc[i][0]*inv, acc[i][1]*inv, acc[i][2]*inv, acc[i][3]*inv };
        *(float4*)&u[(size_t)(b*1024 + l0 + lr)*512 + hd*64 + tx*4] = o;
    }
}

// ---------------------------------------------------------------------------
// K7: out = U[2048,512] @ wo[512,512] + wo_b.  grid (8, 32), 256 thr.
// ---------------------------------------------------------------------------
__global__ __launch_bounds__(256) void k_out(
    const float* __restrict__ uu, const float* __restrict__ wo,
    const float* __restrict__ bo, float* __restrict__ out)
{
    const int tid = threadIdx.x;
    const int tx = tid & 15, ty = tid >> 4;
    const int col0 = blockIdx.x * 64;
    const int row0 = blockIdx.y * 64;

    __shared__ float xs[64][17];
    __shared__ __align__(16) float wsb[16][68];
    float acc[4][4] = {};

    const float4* x4 = (const float4*)uu;
    const float4* w4 = (const float4*)wo;
    for (int k0 = 0; k0 < 512; k0 += 16) {
        {
            int r = tid >> 2, c4 = tid & 3;
            float4 t = x4[(size_t)(row0 + r) * 128 + (k0 >> 2) + c4];
            xs[r][c4*4+0] = t.x; xs[r][c4*4+1] = t.y;
            xs[r][c4*4+2] = t.z; xs[r][c4*4+3] = t.w;
        }
        {
            int r = tid >> 4, c4 = tid & 15;
            float4 t = w4[(size_t)(k0 + r) * 128 + (col0 >> 2) + c4];
            *(float4*)&wsb[r][c4*4] = t;
        }
        __syncthreads();
        #pragma unroll
        for (int kk = 0; kk < 16; ++kk) {
            float a[4];
            a[0] = xs[ty*4+0][kk]; a[1] = xs[ty*4+1][kk];
            a[2] = xs[ty*4+2][kk]; a[3] = xs[ty*4+3][kk];
            float4 b4 = *(const float4*)&wsb[kk][tx*4];
            float bb[4] = {b4.x, b4.y, b4.z, b4.w};
            #pragma unroll
            for (int ii = 0; ii < 4; ++ii)
                #pragma unroll
                for (int jj = 0; jj < 4; ++jj)
                    acc[ii][jj] += a[ii] * bb[jj];
        }
        __syncthreads();
    }
    const int dd = tx * 4;
    #pragma unroll
    for (int i = 0; i < 4; ++i) {
        float4 o;
        o.x = acc[i][0] + bo[col0+dd+0];
        o.y = acc[i][1] + bo[col0+dd+1];
        o.z = acc[i][2] + bo[col0+dd+2];
        o.w = acc[i][3] + bo[col0+dd+3];
        *(float4*)&out[(size_t)(row0 + ty*4 + i) * 512 + col0 + dd] = o;
    }
}

extern "C" void kernel_launch(void* const* d_in, const int* in_sizes, int n_in,
                              void* d_out, int out_size, void* d_ws, size_t ws_size,
                              hipStream_t stream)
{
    const float* x   = (const float*)d_in[0];
    const float* sb  = (const float*)d_in[1];
    const float* wq  = (const float*)d_in[2];
    const float* bq  = (const float*)d_in[3];
    const float* wk  = (const float*)d_in[4];
    const float* bk  = (const float*)d_in[5];
    const float* wv  = (const float*)d_in[6];
    const float* bv  = (const float*)d_in[7];
    const float* wo  = (const float*)d_in[8];
    const float* bo  = (const float*)d_in[9];
    const float* wg  = (const float*)d_in[10];
    const float* wgb = (const float*)d_in[11];
    float* out = (float*)d_out;
    float* ws  = (float*)d_ws;

    // workspace layout (floats)
    float* Q   = ws;                    // 1048576  [B,H,L,64]
    float* Kt  = ws + 1048576;          // 1048576  (scaled k)
    float* V   = ws + 2*1048576;        // 1048576
    float* KC  = ws + 3*1048576;        // 1048576  k_conv (atomic-accumulated)
    float* VC  = ws + 4*1048576;        // 1048576  v_conv (atomic-accumulated)
    float* GL  = ws + 5*1048576;        // 16384    gates g
    float* WGT = GL + 16384;            // 16384    w_j = g_j*c_j
    float* AP  = WGT + 16384;           // 4*65536  A partials
    float* U   = AP + 4*65536;          // 1048576  unit vectors [B,L,D]

    // zero the conv accumulators (KC and VC are adjacent: 2M floats = 8 MB)
    hipMemsetAsync(KC, 0, 2u * 1048576u * sizeof(float), stream);

    k_qkv <<<dim3(8, 32, 3),  256, 0, stream>>>(x, wq, bq, wk, bk, wv, bv, Q, Kt, V);
    k_conv<<<dim3(16, 8, 32), 256, 0, stream>>>(sb, Kt, V, KC, VC);
    k_gate<<<dim3(16, 16),    256, 0, stream>>>(KC, VC, wg, wgb, GL);
    k_scan<<<dim3(16),        256, 0, stream>>>(GL, WGT);
    k_amat<<<dim3(16, 4),     256, 0, stream>>>(KC, VC, WGT, AP);
    k_ctxt<<<dim3(16, 16),    256, 0, stream>>>(Q, AP, U);
    k_out <<<dim3(8, 32),     256, 0, stream>>>(U, wo, bo, out);
}

// Round 3
// 252.792 us; speedup vs baseline: 1.3488x; 1.3488x over previous
//
#include <hip/hip_runtime.h>
#include <math.h>

// Problem constants: B=2, L=1024, D=512, H=8, h=64, K=H=8, EPS=1e-5
// Layouts: q/k/v/k_conv/v_conv stored as [B*H][L][64] (bh*65536 + l*64 + d)

// ---------------------------------------------------------------------------
// K1: fused QKV projection.  x[2048,512] @ W[512,512] (+bias)*scale, written
// into [B,H,L,h] layout.  grid (8 colTiles, 32 rowTiles, 3 weights), 256 thr.
// ---------------------------------------------------------------------------
__global__ __launch_bounds__(256) void k_qkv(
    const float* __restrict__ x,
    const float* __restrict__ wq, const float* __restrict__ bq,
    const float* __restrict__ wk, const float* __restrict__ bk,
    const float* __restrict__ wv, const float* __restrict__ bv,
    float* __restrict__ qo, float* __restrict__ ko, float* __restrict__ vo)
{
    const int tid = threadIdx.x;
    const int tx = tid & 15, ty = tid >> 4;
    const int col0 = blockIdx.x * 64;   // head = blockIdx.x (64 cols per head)
    const int row0 = blockIdx.y * 64;
    const float* w; const float* bias; float* dst; float scale;
    if (blockIdx.z == 0)      { w = wq; bias = bq; dst = qo; scale = 1.0f;   }
    else if (blockIdx.z == 1) { w = wk; bias = bk; dst = ko; scale = 0.125f; } // h^-0.5
    else                      { w = wv; bias = bv; dst = vo; scale = 1.0f;   }

    __shared__ float xs[64][17];
    __shared__ __align__(16) float wsb[16][68];
    float acc[4][4] = {};

    const float4* x4 = (const float4*)x;
    const float4* w4 = (const float4*)w;
    for (int k0 = 0; k0 < 512; k0 += 16) {
        {   // load x tile 64x16
            int r = tid >> 2, c4 = tid & 3;
            float4 t = x4[(size_t)(row0 + r) * 128 + (k0 >> 2) + c4];
            xs[r][c4*4+0] = t.x; xs[r][c4*4+1] = t.y;
            xs[r][c4*4+2] = t.z; xs[r][c4*4+3] = t.w;
        }
        {   // load w tile 16x64
            int r = tid >> 4, c4 = tid & 15;
            float4 t = w4[(size_t)(k0 + r) * 128 + (col0 >> 2) + c4];
            *(float4*)&wsb[r][c4*4] = t;
        }
        __syncthreads();
        #pragma unroll
        for (int kk = 0; kk < 16; ++kk) {
            float a[4];
            a[0] = xs[ty*4+0][kk]; a[1] = xs[ty*4+1][kk];
            a[2] = xs[ty*4+2][kk]; a[3] = xs[ty*4+3][kk];
            float4 b4 = *(const float4*)&wsb[kk][tx*4];
            float bb[4] = {b4.x, b4.y, b4.z, b4.w};
            #pragma unroll
            for (int ii = 0; ii < 4; ++ii)
                #pragma unroll
                for (int jj = 0; jj < 4; ++jj)
                    acc[ii][jj] += a[ii] * bb[jj];
        }
        __syncthreads();
    }

    const int b  = row0 >> 10;
    const int hd = blockIdx.x;
    const int dd = tx * 4;
    #pragma unroll
    for (int i = 0; i < 4; ++i) {
        int l = (row0 & 1023) + ty*4 + i;
        float4 o;
        o.x = (acc[i][0] + bias[col0+dd+0]) * scale;
        o.y = (acc[i][1] + bias[col0+dd+1]) * scale;
        o.z = (acc[i][2] + bias[col0+dd+2]) * scale;
        o.w = (acc[i][3] + bias[col0+dd+3]) * scale;
        *(float4*)&dst[(size_t)((b*8 + hd)*1024 + l) * 64 + dd] = o;
    }
}

// ---------------------------------------------------------------------------
// Compact slot table for s-chunks of 256: tile i has i/4+1 contributing
// chunks; S(i) = prefix sum of counts.  Total slots = 40 per bh-tensor.
// ---------------------------------------------------------------------------
__device__ __forceinline__ int slot_base(int i) {
    return (i < 4) ? i
         : (i < 8) ? 4  + 2*(i-4)
         : (i < 12)? 12 + 3*(i-8)
         :           24 + 4*(i-12);
}

// ---------------------------------------------------------------------------
// K2a: causal Toeplitz conv partials.  y[t,d] += sum_{s in chunk} f[t-s]*u[s,d]
// grid (16 tTiles, 4 sChunks of 256, 32 = tensor*16 + bh), 256 thr.
// Each active block writes its 64x64 partial to a private slot (no atomics).
// ---------------------------------------------------------------------------
__global__ __launch_bounds__(256) void k_conv_part(
    const float* __restrict__ sb,
    const float* __restrict__ kin, const float* __restrict__ vin,
    float* __restrict__ P)
{
    const int tid = threadIdx.x, tx = tid & 15, ty = tid >> 4;
    const int it  = blockIdx.x;          // t-tile
    const int t0  = it * 64;
    const int sc  = blockIdx.y;          // s-chunk
    const int bht = blockIdx.z;          // tensor*16 + bh
    const int bh  = bht & 15;
    const int hd  = bh & 7;
    const int sbeg = sc * 256;
    if (sbeg >= t0 + 64) return;         // block-uniform early exit
    const int send = min(sbeg + 256, t0 + 64);

    const float* src = ((bht >> 4) ? vin : kin) + (size_t)bh * 65536;

    __shared__ __align__(16) float us[16][68];
    __shared__ __align__(16) float fwin[80];
    float acc[4][4] = {};

    const float4* s4 = (const float4*)src;
    for (int s0 = sbeg; s0 < send; s0 += 16) {
        const int base = t0 - s0 - 15;
        if (tid < 80) {
            int idx = base + tid;
            fwin[tid] = (idx >= 0 && idx < 1024) ? sb[idx*8 + hd] : 0.0f;
        }
        {
            int r = tid >> 4, c4 = tid & 15;
            float4 t = s4[(size_t)(s0 + r) * 16 + c4];
            *(float4*)&us[r][c4*4] = t;
        }
        __syncthreads();
        // cache the 20-float filter window this thread needs into registers
        float fr[20];
        #pragma unroll
        for (int q = 0; q < 5; ++q) {
            float4 t = *(const float4*)&fwin[ty*4 + q*4];
            fr[q*4+0] = t.x; fr[q*4+1] = t.y; fr[q*4+2] = t.z; fr[q*4+3] = t.w;
        }
        #pragma unroll
        for (int kk = 0; kk < 16; ++kk) {
            // f[t-s], t = t0+ty*4+ii, s = s0+kk  ->  fr[ii + 15 - kk]
            float4 u4 = *(const float4*)&us[kk][tx*4];
            float uu[4] = {u4.x, u4.y, u4.z, u4.w};
            #pragma unroll
            for (int ii = 0; ii < 4; ++ii) {
                float f = fr[ii + 15 - kk];
                #pragma unroll
                for (int jj = 0; jj < 4; ++jj)
                    acc[ii][jj] += f * uu[jj];
            }
        }
        __syncthreads();
    }
    const int slot = slot_base(it) + sc;
    float* p = P + ((size_t)bht * 40 + slot) * 4096;
    #pragma unroll
    for (int i = 0; i < 4; ++i) {
        float4 o = { acc[i][0], acc[i][1], acc[i][2], acc[i][3] };
        *(float4*)&p[(ty*4+i)*64 + tx*4] = o;
    }
}

// ---------------------------------------------------------------------------
// K2b: reduce partials -> KC/VC.  grid (16 tTiles, 32 bht), 256 thr.
// ---------------------------------------------------------------------------
__global__ __launch_bounds__(256) void k_conv_reduce(
    const float* __restrict__ P,
    float* __restrict__ kc, float* __restrict__ vc)
{
    const int tid = threadIdx.x;
    const int it  = blockIdx.x;
    const int t0  = it * 64;
    const int bht = blockIdx.y;
    const int bh  = bht & 15;
    const int nc  = it/4 + 1;
    const int sb0 = slot_base(it);

    float* dst = ((bht >> 4) ? vc : kc) + (size_t)bh * 65536;
    const float4* P4 = (const float4*)(P + ((size_t)bht * 40 + sb0) * 4096);

    const int r0 = tid >> 4, c4 = tid & 15;   // 16 rows x 16 float4-cols
    #pragma unroll
    for (int g = 0; g < 4; ++g) {
        int r = g*16 + r0;
        float4 a = P4[r*16 + c4];
        for (int c = 1; c < nc; ++c) {
            float4 t = P4[(size_t)c*1024 + r*16 + c4];
            a.x += t.x; a.y += t.y; a.z += t.z; a.w += t.w;
        }
        *(float4*)&dst[(size_t)(t0 + r)*64 + c4*4] = a;
    }
}

// ---------------------------------------------------------------------------
// K3: gate values.  T = K_conv @ Wg^T (T[l,m] = sum_n k[l,n]*wg[m*64+n]),
// logit[l] = sum_m v[l,m]*T[l,m] + wg_b; g = relu(logit)^2 + EPS.
// grid (16 lTiles, 16 bh), 256 thr.
// ---------------------------------------------------------------------------
__global__ __launch_bounds__(256) void k_gate(
    const float* __restrict__ kc, const float* __restrict__ vc,
    const float* __restrict__ wg_w, const float* __restrict__ wg_b,
    float* __restrict__ gl)
{
    const int tid = threadIdx.x, tx = tid & 15, ty = tid >> 4;
    const int l0 = blockIdx.x * 64;
    const int bh = blockIdx.y;
    const float* kb = kc + (size_t)bh * 65536;
    const float* vb = vc + (size_t)bh * 65536;

    __shared__ float ks[64][17];
    __shared__ __align__(16) float wsh[16][68];
    float acc[4][4] = {};
    const float4* k4 = (const float4*)kb;
    for (int n0 = 0; n0 < 64; n0 += 16) {
        {
            int r = tid >> 2, c4 = tid & 3;
            float4 t = k4[(size_t)(l0 + r) * 16 + (n0 >> 2) + c4];
            ks[r][c4*4+0]=t.x; ks[r][c4*4+1]=t.y; ks[r][c4*4+2]=t.z; ks[r][c4*4+3]=t.w;
        }
        for (int i = tid; i < 1024; i += 256) {   // wsh[nn][m] = wg[m*64 + n0+nn]
            int r = i >> 6, c = i & 63;
            wsh[r][c] = wg_w[c*64 + n0 + r];
        }
        __syncthreads();
        #pragma unroll
        for (int kk = 0; kk < 16; ++kk) {
            float a[4];
            a[0] = ks[ty*4+0][kk]; a[1] = ks[ty*4+1][kk];
            a[2] = ks[ty*4+2][kk]; a[3] = ks[ty*4+3][kk];
            float4 b4 = *(const float4*)&wsh[kk][tx*4];
            float bb[4] = {b4.x, b4.y, b4.z, b4.w};
            #pragma unroll
            for (int ii = 0; ii < 4; ++ii)
                #pragma unroll
                for (int jj = 0; jj < 4; ++jj)
                    acc[ii][jj] += a[ii] * bb[jj];
        }
        __syncthreads();
    }
    __shared__ float red[64][17];
    const float wgb = wg_b[0];
    const float4* v4p = (const float4*)vb;
    #pragma unroll
    for (int i = 0; i < 4; ++i) {
        int lr = ty*4 + i;
        float4 vv = v4p[(size_t)(l0 + lr) * 16 + tx];
        red[lr][tx] = acc[i][0]*vv.x + acc[i][1]*vv.y + acc[i][2]*vv.z + acc[i][3]*vv.w;
    }
    __syncthreads();
    if (tid < 64) {
        float s = 0.0f;
        #pragma unroll
        for (int t = 0; t < 16; ++t) s += red[tid][t];
        float logit = s + wgb;
        float r = fmaxf(logit, 0.0f);
        gl[bh*1024 + l0 + tid] = r*r + 1e-5f;
    }
}

// ---------------------------------------------------------------------------
// K4: scans.  G_l = prefix(g), r_l = 1/(G_l+EPS), c_j = suffix(r),
// w_j = g_j * c_j.  One block per bh, 256 thr x 4 elems.
// ---------------------------------------------------------------------------
__global__ __launch_bounds__(256) void k_scan(
    const float* __restrict__ gl, float* __restrict__ wgt)
{
    const int tid = threadIdx.x, bh = blockIdx.x;
    __shared__ float sbuf[256];
    const float4 g4 = ((const float4*)(gl + bh*1024))[tid];
    float g[4] = {g4.x, g4.y, g4.z, g4.w};
    float p[4];
    p[0]=g[0]; p[1]=p[0]+g[1]; p[2]=p[1]+g[2]; p[3]=p[2]+g[3];
    const float s = p[3];
    sbuf[tid] = s;
    __syncthreads();
    for (int off = 1; off < 256; off <<= 1) {
        float t = (tid >= off) ? sbuf[tid-off] : 0.0f;
        __syncthreads();
        sbuf[tid] += t;
        __syncthreads();
    }
    const float base = sbuf[tid] - s;     // exclusive prefix of g-partials
    float r[4], pr[4];
    #pragma unroll
    for (int u = 0; u < 4; ++u) r[u] = 1.0f / (base + p[u] + 1e-5f);
    pr[0]=r[0]; pr[1]=pr[0]+r[1]; pr[2]=pr[1]+r[2]; pr[3]=pr[2]+r[3];
    const float sr = pr[3];
    __syncthreads();
    sbuf[tid] = sr;
    __syncthreads();
    for (int off = 1; off < 256; off <<= 1) {
        float t = (tid >= off) ? sbuf[tid-off] : 0.0f;
        __syncthreads();
        sbuf[tid] += t;
        __syncthreads();
    }
    const float Rtot  = sbuf[255];
    const float baser = sbuf[tid] - sr;
    float4 o;
    o.x = g[0] * (Rtot - (baser + pr[0]) + r[0]);
    o.y = g[1] * (Rtot - (baser + pr[1]) + r[1]);
    o.z = g[2] * (Rtot - (baser + pr[2]) + r[2]);
    o.w = g[3] * (Rtot - (baser + pr[3]) + r[3]);
    ((float4*)(wgt + bh*1024))[tid] = o;
}

// ---------------------------------------------------------------------------
// K5: A_part[slc][bh] = sum_{j in slice} w_j * outer(v_conv[j], k_conv[j]).
// grid (16 bh, 4 slices), 256 thr, 64x64 output per block.
// ---------------------------------------------------------------------------
__global__ __launch_bounds__(256) void k_amat(
    const float* __restrict__ kc, const float* __restrict__ vc,
    const float* __restrict__ wgt, float* __restrict__ apart)
{
    const int tid = threadIdx.x, tx = tid & 15, ty = tid >> 4;
    const int bh = blockIdx.x, slc = blockIdx.y;
    const float* kb = kc + (size_t)bh * 65536;
    const float* vb = vc + (size_t)bh * 65536;
    const float* wb = wgt + bh*1024;

    __shared__ __align__(16) float vs[16][68];
    __shared__ __align__(16) float ks2[16][68];
    __shared__ float ww[16];
    float acc[4][4] = {};
    const float4* k4 = (const float4*)kb;
    const float4* v4 = (const float4*)vb;
    for (int j0 = slc*256; j0 < slc*256 + 256; j0 += 16) {
        if (tid < 16) ww[tid] = wb[j0 + tid];
        {
            int r = tid >> 4, c4 = tid & 15;
            *(float4*)&vs[r][c4*4]  = v4[(size_t)(j0 + r)*16 + c4];
            *(float4*)&ks2[r][c4*4] = k4[(size_t)(j0 + r)*16 + c4];
        }
        __syncthreads();
        #pragma unroll
        for (int jj = 0; jj < 16; ++jj) {
            float wj = ww[jj];
            float a[4];
            a[0] = vs[jj][ty*4+0]*wj; a[1] = vs[jj][ty*4+1]*wj;
            a[2] = vs[jj][ty*4+2]*wj; a[3] = vs[jj][ty*4+3]*wj;
            float4 b4 = *(const float4*)&ks2[jj][tx*4];
            float bb[4] = {b4.x, b4.y, b4.z, b4.w};
            #pragma unroll
            for (int ii = 0; ii < 4; ++ii)
                #pragma unroll
                for (int jc = 0; jc < 4; ++jc)
                    acc[ii][jc] += a[ii] * bb[jc];
        }
        __syncthreads();
    }
    float* ap = apart + (size_t)(slc*16 + bh) * 4096;
    #pragma unroll
    for (int i = 0; i < 4; ++i) {
        float4 o = { acc[i][0], acc[i][1], acc[i][2], acc[i][3] };
        *(float4*)&ap[(ty*4+i)*64 + tx*4] = o;
    }
}

// ---------------------------------------------------------------------------
// K6: ctxt = q @ A (summing the 4 A-partials on load), row-normalize,
// write unit vectors into [B,L,D] layout.  grid (16 lTiles, 16 bh), 256 thr.
// ---------------------------------------------------------------------------
__global__ __launch_bounds__(256) void k_ctxt(
    const float* __restrict__ q, const float* __restrict__ apart,
    float* __restrict__ u)
{
    const int tid = threadIdx.x, tx = tid & 15, ty = tid >> 4;
    const int l0 = blockIdx.x * 64;
    const int bh = blockIdx.y;
    const float* qb = q + (size_t)bh * 65536;

    __shared__ float qs[64][17];
    __shared__ __align__(16) float As[16][68];
    float acc[4][4] = {};
    const float4* q4 = (const float4*)qb;
    const float4* a4 = (const float4*)apart;
    for (int d0 = 0; d0 < 64; d0 += 16) {
        {
            int r = tid >> 2, c4 = tid & 3;
            float4 t = q4[(size_t)(l0 + r)*16 + (d0 >> 2) + c4];
            qs[r][c4*4+0]=t.x; qs[r][c4*4+1]=t.y; qs[r][c4*4+2]=t.z; qs[r][c4*4+3]=t.w;
        }
        {
            int r = tid >> 4, c4 = tid & 15;
            size_t o = (size_t)(d0 + r)*16 + c4;
            float4 t0 = a4[(size_t)(0*16 + bh)*1024 + o];
            float4 t1 = a4[(size_t)(1*16 + bh)*1024 + o];
            float4 t2 = a4[(size_t)(2*16 + bh)*1024 + o];
            float4 t3 = a4[(size_t)(3*16 + bh)*1024 + o];
            float4 t;
            t.x = t0.x+t1.x+t2.x+t3.x; t.y = t0.y+t1.y+t2.y+t3.y;
            t.z = t0.z+t1.z+t2.z+t3.z; t.w = t0.w+t1.w+t2.w+t3.w;
            *(float4*)&As[r][c4*4] = t;
        }
        __syncthreads();
        #pragma unroll
        for (int dd = 0; dd < 16; ++dd) {
            float a[4];
            a[0] = qs[ty*4+0][dd]; a[1] = qs[ty*4+1][dd];
            a[2] = qs[ty*4+2][dd]; a[3] = qs[ty*4+3][dd];
            float4 b4 = *(const float4*)&As[dd][tx*4];
            float bb[4] = {b4.x, b4.y, b4.z, b4.w};
            #pragma unroll
            for (int ii = 0; ii < 4; ++ii)
                #pragma unroll
                for (int jj = 0; jj < 4; ++jj)
                    acc[ii][jj] += a[ii] * bb[jj];
        }
        __syncthreads();
    }
    __shared__ float red[64][17];
    __shared__ float nrm[64];
    #pragma unroll
    for (int i = 0; i < 4; ++i) {
        red[ty*4+i][tx] = acc[i][0]*acc[i][0] + acc[i][1]*acc[i][1]
                        + acc[i][2]*acc[i][2] + acc[i][3]*acc[i][3];
    }
    __syncthreads();
    if (tid < 64) {
        float s = 0.0f;
        #pragma unroll
        for (int t = 0; t < 16; ++t) s += red[tid][t];
        nrm[tid] = fmaxf(sqrtf(s), 1e-5f);
    }
    __syncthreads();
    const int b = bh >> 3, hd = bh & 7;
    #pragma unroll
    for (int i = 0; i < 4; ++i) {
        int lr = ty*4 + i;
        float inv = 1.0f / nrm[lr];
        float4 o = { acc[i][0]*inv, acc[i][1]*inv, acc[i][2]*inv, acc[i][3]*inv };
        *(float4*)&u[(size_t)(b*1024 + l0 + lr)*512 + hd*64 + tx*4] = o;
    }
}

// ---------------------------------------------------------------------------
// K7: out = U[2048,512] @ wo[512,512] + wo_b.  grid (8, 32), 256 thr.
// ---------------------------------------------------------------------------
__global__ __launch_bounds__(256) void k_out(
    const float* __restrict__ uu, const float* __restrict__ wo,
    const float* __restrict__ bo, float* __restrict__ out)
{
    const int tid = threadIdx.x;
    const int tx = tid & 15, ty = tid >> 4;
    const int col0 = blockIdx.x * 64;
    const int row0 = blockIdx.y * 64;

    __shared__ float xs[64][17];
    __shared__ __align__(16) float wsb[16][68];
    float acc[4][4] = {};

    const float4* x4 = (const float4*)uu;
    const float4* w4 = (const float4*)wo;
    for (int k0 = 0; k0 < 512; k0 += 16) {
        {
            int r = tid >> 2, c4 = tid & 3;
            float4 t = x4[(size_t)(row0 + r) * 128 + (k0 >> 2) + c4];
            xs[r][c4*4+0] = t.x; xs[r][c4*4+1] = t.y;
            xs[r][c4*4+2] = t.z; xs[r][c4*4+3] = t.w;
        }
        {
            int r = tid >> 4, c4 = tid & 15;
            float4 t = w4[(size_t)(k0 + r) * 128 + (col0 >> 2) + c4];
            *(float4*)&wsb[r][c4*4] = t;
        }
        __syncthreads();
        #pragma unroll
        for (int kk = 0; kk < 16; ++kk) {
            float a[4];
            a[0] = xs[ty*4+0][kk]; a[1] = xs[ty*4+1][kk];
            a[2] = xs[ty*4+2][kk]; a[3] = xs[ty*4+3][kk];
            float4 b4 = *(const float4*)&wsb[kk][tx*4];
            float bb[4] = {b4.x, b4.y, b4.z, b4.w};
            #pragma unroll
            for (int ii = 0; ii < 4; ++ii)
                #pragma unroll
                for (int jj = 0; jj < 4; ++jj)
                    acc[ii][jj] += a[ii] * bb[jj];
        }
        __syncthreads();
    }
    const int dd = tx * 4;
    #pragma unroll
    for (int i = 0; i < 4; ++i) {
        float4 o;
        o.x = acc[i][0] + bo[col0+dd+0];
        o.y = acc[i][1] + bo[col0+dd+1];
        o.z = acc[i][2] + bo[col0+dd+2];
        o.w = acc[i][3] + bo[col0+dd+3];
        *(float4*)&out[(size_t)(row0 + ty*4 + i) * 512 + col0 + dd] = o;
    }
}

extern "C" void kernel_launch(void* const* d_in, const int* in_sizes, int n_in,
                              void* d_out, int out_size, void* d_ws, size_t ws_size,
                              hipStream_t stream)
{
    const float* x   = (const float*)d_in[0];
    const float* sb  = (const float*)d_in[1];
    const float* wq  = (const float*)d_in[2];
    const float* bq  = (const float*)d_in[3];
    const float* wk  = (const float*)d_in[4];
    const float* bk  = (const float*)d_in[5];
    const float* wv  = (const float*)d_in[6];
    const float* bv  = (const float*)d_in[7];
    const float* wo  = (const float*)d_in[8];
    const float* bo  = (const float*)d_in[9];
    const float* wg  = (const float*)d_in[10];
    const float* wgb = (const float*)d_in[11];
    float* out = (float*)d_out;
    float* ws  = (float*)d_ws;

    // workspace layout (floats)
    float* Q   = ws;                    // 1048576  [B,H,L,64]
    float* Kt  = ws + 1048576;          // 1048576  (scaled k)
    float* V   = ws + 2*1048576;        // 1048576
    float* KC  = ws + 3*1048576;        // 1048576  k_conv
    float* VC  = ws + 4*1048576;        // 1048576  v_conv
    float* P   = ws + 5*1048576;        // 32*40*4096 = 5242880 conv partials
    float* GL  = P + 5242880;           // 16384    gates g
    float* WGT = GL + 16384;            // 16384    w_j = g_j*c_j
    float* AP  = WGT + 16384;           // 4*65536  A partials
    float* U   = AP + 4*65536;          // 1048576  unit vectors [B,L,D]

    k_qkv        <<<dim3(8, 32, 3),  256, 0, stream>>>(x, wq, bq, wk, bk, wv, bv, Q, Kt, V);
    k_conv_part  <<<dim3(16, 4, 32), 256, 0, stream>>>(sb, Kt, V, P);
    k_conv_reduce<<<dim3(16, 32),    256, 0, stream>>>(P, KC, VC);
    k_gate       <<<dim3(16, 16),    256, 0, stream>>>(KC, VC, wg, wgb, GL);
    k_scan       <<<dim3(16),        256, 0, stream>>>(GL, WGT);
    k_amat       <<<dim3(16, 4),     256, 0, stream>>>(KC, VC, WGT, AP);
    k_ctxt       <<<dim3(16, 16),    256, 0, stream>>>(Q, AP, U);
    k_out        <<<dim3(8, 32),     256, 0, stream>>>(U, wo, bo, out);
}

// Round 4
// 205.496 us; speedup vs baseline: 1.6592x; 1.2302x over previous
//
#include <hip/hip_runtime.h>
#include <math.h>

// Problem constants: B=2, L=1024, D=512, H=8, h=64, K=H=8, EPS=1e-5
// Layouts: q/k/v/k_conv/v_conv stored as [B*H][L][64] (bh*65536 + l*64 + d)

typedef __attribute__((ext_vector_type(8))) short short8;
typedef __attribute__((ext_vector_type(4))) float floatx4;

__device__ __forceinline__ unsigned short f2bf(float f) {
    unsigned int u = __float_as_uint(f);
    unsigned int r = (u + 0x7FFFu + ((u >> 16) & 1u)) >> 16;   // RNE
    return (unsigned short)r;
}

// ---------------------------------------------------------------------------
// K0a: cast x[2048*512] fp32 -> bf16.  512 blocks x 256 thr x 8 elems.
// ---------------------------------------------------------------------------
__global__ __launch_bounds__(256) void k_castx(
    const float* __restrict__ x, unsigned short* __restrict__ xb)
{
    const int gid = blockIdx.x * 256 + threadIdx.x;   // 0..131071
    const float4* x4 = (const float4*)x;
    float4 a = x4[gid*2], b = x4[gid*2+1];
    uint4 o;
    o.x = f2bf(a.x) | ((unsigned)f2bf(a.y) << 16);
    o.y = f2bf(a.z) | ((unsigned)f2bf(a.w) << 16);
    o.z = f2bf(b.x) | ((unsigned)f2bf(b.y) << 16);
    o.w = f2bf(b.z) | ((unsigned)f2bf(b.w) << 16);
    ((uint4*)xb)[gid] = o;
}

// ---------------------------------------------------------------------------
// K0b: transpose+cast weights.  wT[1536][512] (rows n: 0-511 wq, 512-1023 wk,
// 1024-1535 wv; wT[n][k] = w[k][n]) and woT[512][512].  256 tiles of 64x64.
// ---------------------------------------------------------------------------
__global__ __launch_bounds__(256) void k_packw(
    const float* __restrict__ wq, const float* __restrict__ wk,
    const float* __restrict__ wv, const float* __restrict__ wo,
    unsigned short* __restrict__ wT, unsigned short* __restrict__ woT)
{
    const int t = blockIdx.x;
    const float* src; unsigned short* dst; int n0, c0, k0;
    if (t < 192) {
        int nt = t >> 3, kt = t & 7;
        n0 = nt * 64; k0 = kt * 64;
        int z = n0 >> 9; c0 = n0 & 511;
        src = (z == 0) ? wq : (z == 1) ? wk : wv;
        dst = wT;
    } else {
        int u = t - 192; int nt = u >> 3, kt = u & 7;
        n0 = nt * 64; c0 = n0; k0 = kt * 64;
        src = wo; dst = woT;
    }
    __shared__ float sf[64][65];
    const int tid = threadIdx.x, rr = tid >> 4, c4 = tid & 15;
    #pragma unroll
    for (int g = 0; g < 4; ++g) {
        int r = g*16 + rr;
        float4 v = *(const float4*)&src[(size_t)(k0 + r)*512 + c0 + c4*4];
        sf[r][c4*4+0]=v.x; sf[r][c4*4+1]=v.y; sf[r][c4*4+2]=v.z; sf[r][c4*4+3]=v.w;
    }
    __syncthreads();
    #pragma unroll
    for (int g = 0; g < 4; ++g) {
        int c = g*16 + rr;          // n within tile
        int kk = c4*4;              // k within tile
        ushort4 o;
        o.x = f2bf(sf[kk+0][c]); o.y = f2bf(sf[kk+1][c]);
        o.z = f2bf(sf[kk+2][c]); o.w = f2bf(sf[kk+3][c]);
        *(ushort4*)&dst[(size_t)(n0 + c)*512 + k0 + kk] = o;
    }
}

// ---------------------------------------------------------------------------
// K1: QKV projection via MFMA.  C[2048][1536] = xb @ wT^T, epilogue scatters
// into [B,H,L,h] with bias and k-scale.  grid (12, 16), 256 thr (4 waves,
// each 64x64 = 4x4 tiles of 16x16x32 bf16 MFMA).
// ---------------------------------------------------------------------------
__global__ __launch_bounds__(256) void k_qkv_mfma(
    const unsigned short* __restrict__ xb, const unsigned short* __restrict__ wT,
    const float* __restrict__ bq, const float* __restrict__ bk,
    const float* __restrict__ bv,
    float* __restrict__ qo, float* __restrict__ ko, float* __restrict__ vo)
{
    const int tid = threadIdx.x;
    const int lane = tid & 63, wave = tid >> 6;
    const int q = lane >> 4, ln = lane & 15;
    const int wm = (wave >> 1) * 64, wn = (wave & 1) * 64;
    const int m0 = blockIdx.y * 128;
    const int n0 = blockIdx.x * 128;

    __shared__ unsigned short As[128*40];   // row stride 40 (80B: 2-way banks)
    __shared__ unsigned short Bs[128*40];

    floatx4 acc[4][4];
    #pragma unroll
    for (int i = 0; i < 4; ++i)
        #pragma unroll
        for (int j = 0; j < 4; ++j)
            acc[i][j] = (floatx4){0.f, 0.f, 0.f, 0.f};

    const uint4* Ag = (const uint4*)xb;     // 8 ushorts per uint4
    const uint4* Bg = (const uint4*)wT;
    for (int k0 = 0; k0 < 512; k0 += 32) {
        #pragma unroll
        for (int s = 0; s < 2; ++s) {
            int c = tid*2 + s;              // 0..511
            int r = c >> 2, cp = c & 3;
            uint4 va = Ag[(size_t)(m0 + r)*64 + (k0 >> 3) + cp];
            uint4 vb = Bg[(size_t)(n0 + r)*64 + (k0 >> 3) + cp];
            *(uint4*)&As[r*40 + cp*8] = va;
            *(uint4*)&Bs[r*40 + cp*8] = vb;
        }
        __syncthreads();
        short8 af[4], bfr[4];
        #pragma unroll
        for (int i = 0; i < 4; ++i) {
            af[i]  = *(const short8*)&As[(wm + i*16 + ln)*40 + q*8];
            bfr[i] = *(const short8*)&Bs[(wn + i*16 + ln)*40 + q*8];
        }
        #pragma unroll
        for (int mi = 0; mi < 4; ++mi)
            #pragma unroll
            for (int ni = 0; ni < 4; ++ni)
                acc[mi][ni] = __builtin_amdgcn_mfma_f32_16x16x32_bf16(
                    af[mi], bfr[ni], acc[mi][ni], 0, 0, 0);
        __syncthreads();
    }

    const int z = n0 >> 9;                  // block never straddles a weight
    const float scale = (z == 1) ? 0.125f : 1.0f;
    const float* bias = (z == 0) ? bq : (z == 1) ? bk : bv;
    float* dst = (z == 0) ? qo : (z == 1) ? ko : vo;
    #pragma unroll
    for (int mi = 0; mi < 4; ++mi) {
        #pragma unroll
        for (int ni = 0; ni < 4; ++ni) {
            int gcol = n0 + wn + ni*16 + ln;
            int c = gcol & 511;
            int head = c >> 6, dd = c & 63;
            float bb = bias[c];
            #pragma unroll
            for (int reg = 0; reg < 4; ++reg) {
                int row = m0 + wm + mi*16 + q*4 + reg;
                int b = row >> 10, l = row & 1023;
                dst[(size_t)((b*8 + head)*1024 + l)*64 + dd] =
                    (acc[mi][ni][reg] + bb) * scale;
            }
        }
    }
}

// ---------------------------------------------------------------------------
// K8: out = Ub[2048][512](bf16) @ woT^T + wo_b via MFMA.  grid (4, 16).
// ---------------------------------------------------------------------------
__global__ __launch_bounds__(256) void k_out_mfma(
    const unsigned short* __restrict__ ub, const unsigned short* __restrict__ woT,
    const float* __restrict__ bo, float* __restrict__ out)
{
    const int tid = threadIdx.x;
    const int lane = tid & 63, wave = tid >> 6;
    const int q = lane >> 4, ln = lane & 15;
    const int wm = (wave >> 1) * 64, wn = (wave & 1) * 64;
    const int m0 = blockIdx.y * 128;
    const int n0 = blockIdx.x * 128;

    __shared__ unsigned short As[128*40];
    __shared__ unsigned short Bs[128*40];

    floatx4 acc[4][4];
    #pragma unroll
    for (int i = 0; i < 4; ++i)
        #pragma unroll
        for (int j = 0; j < 4; ++j)
            acc[i][j] = (floatx4){0.f, 0.f, 0.f, 0.f};

    const uint4* Ag = (const uint4*)ub;
    const uint4* Bg = (const uint4*)woT;
    for (int k0 = 0; k0 < 512; k0 += 32) {
        #pragma unroll
        for (int s = 0; s < 2; ++s) {
            int c = tid*2 + s;
            int r = c >> 2, cp = c & 3;
            uint4 va = Ag[(size_t)(m0 + r)*64 + (k0 >> 3) + cp];
            uint4 vb = Bg[(size_t)(n0 + r)*64 + (k0 >> 3) + cp];
            *(uint4*)&As[r*40 + cp*8] = va;
            *(uint4*)&Bs[r*40 + cp*8] = vb;
        }
        __syncthreads();
        short8 af[4], bfr[4];
        #pragma unroll
        for (int i = 0; i < 4; ++i) {
            af[i]  = *(const short8*)&As[(wm + i*16 + ln)*40 + q*8];
            bfr[i] = *(const short8*)&Bs[(wn + i*16 + ln)*40 + q*8];
        }
        #pragma unroll
        for (int mi = 0; mi < 4; ++mi)
            #pragma unroll
            for (int ni = 0; ni < 4; ++ni)
                acc[mi][ni] = __builtin_amdgcn_mfma_f32_16x16x32_bf16(
                    af[mi], bfr[ni], acc[mi][ni], 0, 0, 0);
        __syncthreads();
    }

    #pragma unroll
    for (int mi = 0; mi < 4; ++mi) {
        #pragma unroll
        for (int ni = 0; ni < 4; ++ni) {
            int gcol = n0 + wn + ni*16 + ln;
            float bb = bo[gcol];
            #pragma unroll
            for (int reg = 0; reg < 4; ++reg) {
                int row = m0 + wm + mi*16 + q*4 + reg;
                out[(size_t)row*512 + gcol] = acc[mi][ni][reg] + bb;
            }
        }
    }
}

// ---------------------------------------------------------------------------
// Compact slot table for s-chunks of 256: tile i has i/4+1 contributing
// chunks.  Total slots = 40 per bh-tensor.
// ---------------------------------------------------------------------------
__device__ __forceinline__ int slot_base(int i) {
    return (i < 4) ? i
         : (i < 8) ? 4  + 2*(i-4)
         : (i < 12)? 12 + 3*(i-8)
         :           24 + 4*(i-12);
}

// ---------------------------------------------------------------------------
// K2a: causal Toeplitz conv partials.  y[t,d] += sum_{s in chunk} f[t-s]*u[s,d]
// grid (16 tTiles, 4 sChunks of 256, 32 = tensor*16 + bh), 256 thr.
// ---------------------------------------------------------------------------
__global__ __launch_bounds__(256) void k_conv_part(
    const float* __restrict__ sb,
    const float* __restrict__ kin, const float* __restrict__ vin,
    float* __restrict__ P)
{
    const int tid = threadIdx.x, tx = tid & 15, ty = tid >> 4;
    const int it  = blockIdx.x;
    const int t0  = it * 64;
    const int sc  = blockIdx.y;
    const int bht = blockIdx.z;
    const int bh  = bht & 15;
    const int hd  = bh & 7;
    const int sbeg = sc * 256;
    if (sbeg >= t0 + 64) return;
    const int send = min(sbeg + 256, t0 + 64);

    const float* src = ((bht >> 4) ? vin : kin) + (size_t)bh * 65536;

    __shared__ __align__(16) float us[16][68];
    __shared__ __align__(16) float fwin[80];
    float acc[4][4] = {};

    const float4* s4 = (const float4*)src;
    for (int s0 = sbeg; s0 < send; s0 += 16) {
        const int base = t0 - s0 - 15;
        if (tid < 80) {
            int idx = base + tid;
            fwin[tid] = (idx >= 0 && idx < 1024) ? sb[idx*8 + hd] : 0.0f;
        }
        {
            int r = tid >> 4, c4 = tid & 15;
            float4 t = s4[(size_t)(s0 + r) * 16 + c4];
            *(float4*)&us[r][c4*4] = t;
        }
        __syncthreads();
        float fr[20];
        #pragma unroll
        for (int qq = 0; qq < 5; ++qq) {
            float4 t = *(const float4*)&fwin[ty*4 + qq*4];
            fr[qq*4+0] = t.x; fr[qq*4+1] = t.y; fr[qq*4+2] = t.z; fr[qq*4+3] = t.w;
        }
        #pragma unroll
        for (int kk = 0; kk < 16; ++kk) {
            float4 u4 = *(const float4*)&us[kk][tx*4];
            float uu[4] = {u4.x, u4.y, u4.z, u4.w};
            #pragma unroll
            for (int ii = 0; ii < 4; ++ii) {
                float f = fr[ii + 15 - kk];
                #pragma unroll
                for (int jj = 0; jj < 4; ++jj)
                    acc[ii][jj] += f * uu[jj];
            }
        }
        __syncthreads();
    }
    const int slot = slot_base(it) + sc;
    float* p = P + ((size_t)bht * 40 + slot) * 4096;
    #pragma unroll
    for (int i = 0; i < 4; ++i) {
        float4 o = { acc[i][0], acc[i][1], acc[i][2], acc[i][3] };
        *(float4*)&p[(ty*4+i)*64 + tx*4] = o;
    }
}

// ---------------------------------------------------------------------------
// K2b: reduce partials -> KC/VC.  grid (16 tTiles, 32 bht), 256 thr.
// ---------------------------------------------------------------------------
__global__ __launch_bounds__(256) void k_conv_reduce(
    const float* __restrict__ P,
    float* __restrict__ kc, float* __restrict__ vc)
{
    const int tid = threadIdx.x;
    const int it  = blockIdx.x;
    const int t0  = it * 64;
    const int bht = blockIdx.y;
    const int bh  = bht & 15;
    const int nc  = it/4 + 1;
    const int sb0 = slot_base(it);

    float* dst = ((bht >> 4) ? vc : kc) + (size_t)bh * 65536;
    const float4* P4 = (const float4*)(P + ((size_t)bht * 40 + sb0) * 4096);

    const int r0 = tid >> 4, c4 = tid & 15;
    #pragma unroll
    for (int g = 0; g < 4; ++g) {
        int r = g*16 + r0;
        float4 a = P4[r*16 + c4];
        for (int c = 1; c < nc; ++c) {
            float4 t = P4[(size_t)c*1024 + r*16 + c4];
            a.x += t.x; a.y += t.y; a.z += t.z; a.w += t.w;
        }
        *(float4*)&dst[(size_t)(t0 + r)*64 + c4*4] = a;
    }
}

// ---------------------------------------------------------------------------
// K3: gate values.  grid (16 lTiles, 16 bh), 256 thr.
// ---------------------------------------------------------------------------
__global__ __launch_bounds__(256) void k_gate(
    const float* __restrict__ kc, const float* __restrict__ vc,
    const float* __restrict__ wg_w, const float* __restrict__ wg_b,
    float* __restrict__ gl)
{
    const int tid = threadIdx.x, tx = tid & 15, ty = tid >> 4;
    const int l0 = blockIdx.x * 64;
    const int bh = blockIdx.y;
    const float* kb = kc + (size_t)bh * 65536;
    const float* vb = vc + (size_t)bh * 65536;

    __shared__ float ks[64][17];
    __shared__ __align__(16) float wsh[16][68];
    float acc[4][4] = {};
    const float4* k4 = (const float4*)kb;
    for (int n0 = 0; n0 < 64; n0 += 16) {
        {
            int r = tid >> 2, c4 = tid & 3;
            float4 t = k4[(size_t)(l0 + r) * 16 + (n0 >> 2) + c4];
            ks[r][c4*4+0]=t.x; ks[r][c4*4+1]=t.y; ks[r][c4*4+2]=t.z; ks[r][c4*4+3]=t.w;
        }
        for (int i = tid; i < 1024; i += 256) {
            int r = i >> 6, c = i & 63;
            wsh[r][c] = wg_w[c*64 + n0 + r];
        }
        __syncthreads();
        #pragma unroll
        for (int kk = 0; kk < 16; ++kk) {
            float a[4];
            a[0] = ks[ty*4+0][kk]; a[1] = ks[ty*4+1][kk];
            a[2] = ks[ty*4+2][kk]; a[3] = ks[ty*4+3][kk];
            float4 b4 = *(const float4*)&wsh[kk][tx*4];
            float bb[4] = {b4.x, b4.y, b4.z, b4.w};
            #pragma unroll
            for (int ii = 0; ii < 4; ++ii)
                #pragma unroll
                for (int jj = 0; jj < 4; ++jj)
                    acc[ii][jj] += a[ii] * bb[jj];
        }
        __syncthreads();
    }
    __shared__ float red[64][17];
    const float wgb = wg_b[0];
    const float4* v4p = (const float4*)vb;
    #pragma unroll
    for (int i = 0; i < 4; ++i) {
        int lr = ty*4 + i;
        float4 vv = v4p[(size_t)(l0 + lr) * 16 + tx];
        red[lr][tx] = acc[i][0]*vv.x + acc[i][1]*vv.y + acc[i][2]*vv.z + acc[i][3]*vv.w;
    }
    __syncthreads();
    if (tid < 64) {
        float s = 0.0f;
        #pragma unroll
        for (int t = 0; t < 16; ++t) s += red[tid][t];
        float logit = s + wgb;
        float r = fmaxf(logit, 0.0f);
        gl[bh*1024 + l0 + tid] = r*r + 1e-5f;
    }
}

// ---------------------------------------------------------------------------
// K4: scans.  One block per bh, 256 thr x 4 elems.
// ---------------------------------------------------------------------------
__global__ __launch_bounds__(256) void k_scan(
    const float* __restrict__ gl, float* __restrict__ wgt)
{
    const int tid = threadIdx.x, bh = blockIdx.x;
    __shared__ float sbuf[256];
    const float4 g4 = ((const float4*)(gl + bh*1024))[tid];
    float g[4] = {g4.x, g4.y, g4.z, g4.w};
    float p[4];
    p[0]=g[0]; p[1]=p[0]+g[1]; p[2]=p[1]+g[2]; p[3]=p[2]+g[3];
    const float s = p[3];
    sbuf[tid] = s;
    __syncthreads();
    for (int off = 1; off < 256; off <<= 1) {
        float t = (tid >= off) ? sbuf[tid-off] : 0.0f;
        __syncthreads();
        sbuf[tid] += t;
        __syncthreads();
    }
    const float base = sbuf[tid] - s;
    float r[4], pr[4];
    #pragma unroll
    for (int u = 0; u < 4; ++u) r[u] = 1.0f / (base + p[u] + 1e-5f);
    pr[0]=r[0]; pr[1]=pr[0]+r[1]; pr[2]=pr[1]+r[2]; pr[3]=pr[2]+r[3];
    const float sr = pr[3];
    __syncthreads();
    sbuf[tid] = sr;
    __syncthreads();
    for (int off = 1; off < 256; off <<= 1) {
        float t = (tid >= off) ? sbuf[tid-off] : 0.0f;
        __syncthreads();
        sbuf[tid] += t;
        __syncthreads();
    }
    const float Rtot  = sbuf[255];
    const float baser = sbuf[tid] - sr;
    float4 o;
    o.x = g[0] * (Rtot - (baser + pr[0]) + r[0]);
    o.y = g[1] * (Rtot - (baser + pr[1]) + r[1]);
    o.z = g[2] * (Rtot - (baser + pr[2]) + r[2]);
    o.w = g[3] * (Rtot - (baser + pr[3]) + r[3]);
    ((float4*)(wgt + bh*1024))[tid] = o;
}

// ---------------------------------------------------------------------------
// K5: A_part[slc][bh] = sum_{j in slice} w_j * outer(v_conv[j], k_conv[j]).
// grid (16 bh, 4 slices), 256 thr.
// ---------------------------------------------------------------------------
__global__ __launch_bounds__(256) void k_amat(
    const float* __restrict__ kc, const float* __restrict__ vc,
    const float* __restrict__ wgt, float* __restrict__ apart)
{
    const int tid = threadIdx.x, tx = tid & 15, ty = tid >> 4;
    const int bh = blockIdx.x, slc = blockIdx.y;
    const float* kb = kc + (size_t)bh * 65536;
    const float* vb = vc + (size_t)bh * 65536;
    const float* wb = wgt + bh*1024;

    __shared__ __align__(16) float vs[16][68];
    __shared__ __align__(16) float ks2[16][68];
    __shared__ float ww[16];
    float acc[4][4] = {};
    const float4* k4 = (const float4*)kb;
    const float4* v4 = (const float4*)vb;
    for (int j0 = slc*256; j0 < slc*256 + 256; j0 += 16) {
        if (tid < 16) ww[tid] = wb[j0 + tid];
        {
            int r = tid >> 4, c4 = tid & 15;
            *(float4*)&vs[r][c4*4]  = v4[(size_t)(j0 + r)*16 + c4];
            *(float4*)&ks2[r][c4*4] = k4[(size_t)(j0 + r)*16 + c4];
        }
        __syncthreads();
        #pragma unroll
        for (int jj = 0; jj < 16; ++jj) {
            float wj = ww[jj];
            float a[4];
            a[0] = vs[jj][ty*4+0]*wj; a[1] = vs[jj][ty*4+1]*wj;
            a[2] = vs[jj][ty*4+2]*wj; a[3] = vs[jj][ty*4+3]*wj;
            float4 b4 = *(const float4*)&ks2[jj][tx*4];
            float bb[4] = {b4.x, b4.y, b4.z, b4.w};
            #pragma unroll
            for (int ii = 0; ii < 4; ++ii)
                #pragma unroll
                for (int jc = 0; jc < 4; ++jc)
                    acc[ii][jc] += a[ii] * bb[jc];
        }
        __syncthreads();
    }
    float* ap = apart + (size_t)(slc*16 + bh) * 4096;
    #pragma unroll
    for (int i = 0; i < 4; ++i) {
        float4 o = { acc[i][0], acc[i][1], acc[i][2], acc[i][3] };
        *(float4*)&ap[(ty*4+i)*64 + tx*4] = o;
    }
}

// ---------------------------------------------------------------------------
// K6: ctxt = q @ A (summing the 4 A-partials on load), row-normalize,
// write unit vectors as bf16 into [B,L,D] layout.  grid (16, 16), 256 thr.
// ---------------------------------------------------------------------------
__global__ __launch_bounds__(256) void k_ctxt(
    const float* __restrict__ q, const float* __restrict__ apart,
    unsigned short* __restrict__ ub)
{
    const int tid = threadIdx.x, tx = tid & 15, ty = tid >> 4;
    const int l0 = blockIdx.x * 64;
    const int bh = blockIdx.y;
    const float* qb = q + (size_t)bh * 65536;

    __shared__ float qs[64][17];
    __shared__ __align__(16) float As[16][68];
    float acc[4][4] = {};
    const float4* q4 = (const float4*)qb;
    const float4* a4 = (const float4*)apart;
    for (int d0 = 0; d0 < 64; d0 += 16) {
        {
            int r = tid >> 2, c4 = tid & 3;
            float4 t = q4[(size_t)(l0 + r)*16 + (d0 >> 2) + c4];
            qs[r][c4*4+0]=t.x; qs[r][c4*4+1]=t.y; qs[r][c4*4+2]=t.z; qs[r][c4*4+3]=t.w;
        }
        {
            int r = tid >> 4, c4 = tid & 15;
            size_t o = (size_t)(d0 + r)*16 + c4;
            float4 t0 = a4[(size_t)(0*16 + bh)*1024 + o];
            float4 t1 = a4[(size_t)(1*16 + bh)*1024 + o];
            float4 t2 = a4[(size_t)(2*16 + bh)*1024 + o];
            float4 t3 = a4[(size_t)(3*16 + bh)*1024 + o];
            float4 t;
            t.x = t0.x+t1.x+t2.x+t3.x; t.y = t0.y+t1.y+t2.y+t3.y;
            t.z = t0.z+t1.z+t2.z+t3.z; t.w = t0.w+t1.w+t2.w+t3.w;
            *(float4*)&As[r][c4*4] = t;
        }
        __syncthreads();
        #pragma unroll
        for (int dd = 0; dd < 16; ++dd) {
            float a[4];
            a[0] = qs[ty*4+0][dd]; a[1] = qs[ty*4+1][dd];
            a[2] = qs[ty*4+2][dd]; a[3] = qs[ty*4+3][dd];
            float4 b4 = *(const float4*)&As[dd][tx*4];
            float bb[4] = {b4.x, b4.y, b4.z, b4.w};
            #pragma unroll
            for (int ii = 0; ii < 4; ++ii)
                #pragma unroll
                for (int jj = 0; jj < 4; ++jj)
                    acc[ii][jj] += a[ii] * bb[jj];
        }
        __syncthreads();
    }
    __shared__ float red[64][17];
    __shared__ float nrm[64];
    #pragma unroll
    for (int i = 0; i < 4; ++i) {
        red[ty*4+i][tx] = acc[i][0]*acc[i][0] + acc[i][1]*acc[i][1]
                        + acc[i][2]*acc[i][2] + acc[i][3]*acc[i][3];
    }
    __syncthreads();
    if (tid < 64) {
        float s = 0.0f;
        #pragma unroll
        for (int t = 0; t < 16; ++t) s += red[tid][t];
        nrm[tid] = fmaxf(sqrtf(s), 1e-5f);
    }
    __syncthreads();
    const int b = bh >> 3, hd = bh & 7;
    #pragma unroll
    for (int i = 0; i < 4; ++i) {
        int lr = ty*4 + i;
        float inv = 1.0f / nrm[lr];
        ushort4 o;
        o.x = f2bf(acc[i][0]*inv); o.y = f2bf(acc[i][1]*inv);
        o.z = f2bf(acc[i][2]*inv); o.w = f2bf(acc[i][3]*inv);
        *(ushort4*)&ub[(size_t)(b*1024 + l0 + lr)*512 + hd*64 + tx*4] = o;
    }
}

extern "C" void kernel_launch(void* const* d_in, const int* in_sizes, int n_in,
                              void* d_out, int out_size, void* d_ws, size_t ws_size,
                              hipStream_t stream)
{
    const float* x   = (const float*)d_in[0];
    const float* sb  = (const float*)d_in[1];
    const float* wq  = (const float*)d_in[2];
    const float* bq  = (const float*)d_in[3];
    const float* wk  = (const float*)d_in[4];
    const float* bk  = (const float*)d_in[5];
    const float* wv  = (const float*)d_in[6];
    const float* bv  = (const float*)d_in[7];
    const float* wo  = (const float*)d_in[8];
    const float* bo  = (const float*)d_in[9];
    const float* wg  = (const float*)d_in[10];
    const float* wgb = (const float*)d_in[11];
    float* out = (float*)d_out;
    float* ws  = (float*)d_ws;

    // workspace layout (float offsets)
    float* Q   = ws;                        // 1048576  [B,H,L,64]
    float* Kt  = ws + 1048576;              // 1048576  (scaled k)
    float* V   = ws + 2*1048576;            // 1048576
    float* KC  = ws + 3*1048576;            // 1048576
    float* VC  = ws + 4*1048576;            // 1048576
    float* P   = ws + 5*1048576;            // 5242880 conv partials
    unsigned short* XB = (unsigned short*)P;        // aliases P: XB dead
                                                    // before conv_part writes P
    float* GL  = ws + 10485760;             // 16384
    float* WGT = GL + 16384;                // 16384
    float* AP  = WGT + 16384;               // 262144
    unsigned short* WT  = (unsigned short*)(AP + 262144);      // 1536*512 bf16
    unsigned short* WOT = (unsigned short*)(AP + 262144 + 393216); // 512*512
    unsigned short* UB  = (unsigned short*)(AP + 262144 + 393216 + 131072);
                                            // 2048*512 bf16 (524288 floats)

    k_castx      <<<dim3(512),       256, 0, stream>>>(x, XB);
    k_packw      <<<dim3(256),       256, 0, stream>>>(wq, wk, wv, wo, WT, WOT);
    k_qkv_mfma   <<<dim3(12, 16),    256, 0, stream>>>(XB, WT, bq, bk, bv, Q, Kt, V);
    k_conv_part  <<<dim3(16, 4, 32), 256, 0, stream>>>(sb, Kt, V, P);
    k_conv_reduce<<<dim3(16, 32),    256, 0, stream>>>(P, KC, VC);
    k_gate       <<<dim3(16, 16),    256, 0, stream>>>(KC, VC, wg, wgb, GL);
    k_scan       <<<dim3(16),        256, 0, stream>>>(GL, WGT);
    k_amat       <<<dim3(16, 4),     256, 0, stream>>>(KC, VC, WGT, AP);
    k_ctxt       <<<dim3(16, 16),    256, 0, stream>>>(Q, AP, UB);
    k_out_mfma   <<<dim3(4, 16),     256, 0, stream>>>(UB, WOT, bo, out);
}

// Round 5
// 190.293 us; speedup vs baseline: 1.7918x; 1.0799x over previous
//
#include <hip/hip_runtime.h>
#include <math.h>

// Problem constants: B=2, L=1024, D=512, H=8, h=64, K=H=8, EPS=1e-5
// Layouts: q/kc/vc stored as [B*H][L][64] (bh*65536 + l*64 + d)
// UB2: bf16 conv inputs, d-major [tensor][bh][d=64][l=1024]
// TB:  bf16 Toeplitz filters [h=8][t=1024][s=1024], zero above diagonal

typedef __attribute__((ext_vector_type(8))) short short8;
typedef __attribute__((ext_vector_type(4))) float floatx4;

__device__ __forceinline__ unsigned short f2bf(float f) {
    unsigned int u = __float_as_uint(f);
    unsigned int r = (u + 0x7FFFu + ((u >> 16) & 1u)) >> 16;   // RNE
    return (unsigned short)r;
}

// ---------------------------------------------------------------------------
// K0a: cast x[2048*512] fp32 -> bf16.  512 blocks x 256 thr x 8 elems.
// ---------------------------------------------------------------------------
__global__ __launch_bounds__(256) void k_castx(
    const float* __restrict__ x, unsigned short* __restrict__ xb)
{
    const int gid = blockIdx.x * 256 + threadIdx.x;
    const float4* x4 = (const float4*)x;
    float4 a = x4[gid*2], b = x4[gid*2+1];
    uint4 o;
    o.x = f2bf(a.x) | ((unsigned)f2bf(a.y) << 16);
    o.y = f2bf(a.z) | ((unsigned)f2bf(a.w) << 16);
    o.z = f2bf(b.x) | ((unsigned)f2bf(b.y) << 16);
    o.w = f2bf(b.z) | ((unsigned)f2bf(b.w) << 16);
    ((uint4*)xb)[gid] = o;
}

// ---------------------------------------------------------------------------
// K0b: transpose+cast weights.  wT[1536][512], woT[512][512] (bf16, n-major).
// ---------------------------------------------------------------------------
__global__ __launch_bounds__(256) void k_packw(
    const float* __restrict__ wq, const float* __restrict__ wk,
    const float* __restrict__ wv, const float* __restrict__ wo,
    unsigned short* __restrict__ wT, unsigned short* __restrict__ woT)
{
    const int t = blockIdx.x;
    const float* src; unsigned short* dst; int n0, c0, k0;
    if (t < 192) {
        int nt = t >> 3, kt = t & 7;
        n0 = nt * 64; k0 = kt * 64;
        int z = n0 >> 9; c0 = n0 & 511;
        src = (z == 0) ? wq : (z == 1) ? wk : wv;
        dst = wT;
    } else {
        int u = t - 192; int nt = u >> 3, kt = u & 7;
        n0 = nt * 64; c0 = n0; k0 = kt * 64;
        src = wo; dst = woT;
    }
    __shared__ float sf[64][65];
    const int tid = threadIdx.x, rr = tid >> 4, c4 = tid & 15;
    #pragma unroll
    for (int g = 0; g < 4; ++g) {
        int r = g*16 + rr;
        float4 v = *(const float4*)&src[(size_t)(k0 + r)*512 + c0 + c4*4];
        sf[r][c4*4+0]=v.x; sf[r][c4*4+1]=v.y; sf[r][c4*4+2]=v.z; sf[r][c4*4+3]=v.w;
    }
    __syncthreads();
    #pragma unroll
    for (int g = 0; g < 4; ++g) {
        int c = g*16 + rr;
        int kk = c4*4;
        ushort4 o;
        o.x = f2bf(sf[kk+0][c]); o.y = f2bf(sf[kk+1][c]);
        o.z = f2bf(sf[kk+2][c]); o.w = f2bf(sf[kk+3][c]);
        *(ushort4*)&dst[(size_t)(n0 + c)*512 + k0 + kk] = o;
    }
}

// ---------------------------------------------------------------------------
// K0c: materialize Toeplitz filters TB[h][t][s] = (t>=s) ? sb[(t-s)*8+h] : 0
// as bf16.  grid (8 heads, 32 rowTiles of 32), 256 thr.
// ---------------------------------------------------------------------------
__global__ __launch_bounds__(256) void k_mkT(
    const float* __restrict__ sb, unsigned short* __restrict__ TB)
{
    const int h = blockIdx.x;
    const int r0 = blockIdx.y * 32;
    __shared__ unsigned short sbc[1024];
    const int tid = threadIdx.x;
    for (int i = tid; i < 1024; i += 256)
        sbc[i] = f2bf(sb[i*8 + h]);
    __syncthreads();
    const int rr = tid >> 3, c0 = (tid & 7) * 128;
    const int t = r0 + rr;
    unsigned short* row = TB + ((size_t)h * 1024 + t) * 1024;
    for (int c = c0; c < c0 + 128; c += 8) {
        unsigned short v[8];
        #pragma unroll
        for (int j = 0; j < 8; ++j) {
            int s = c + j;
            v[j] = (t >= s) ? sbc[t - s] : (unsigned short)0;
        }
        uint4 o;
        o.x = v[0] | ((unsigned)v[1]<<16);
        o.y = v[2] | ((unsigned)v[3]<<16);
        o.z = v[4] | ((unsigned)v[5]<<16);
        o.w = v[6] | ((unsigned)v[7]<<16);
        *(uint4*)&row[c] = o;
    }
}

// ---------------------------------------------------------------------------
// K1: QKV projection via MFMA.  C[2048][1536] = xb @ wT^T.  q -> fp32 [bh][l][64];
// k (scaled), v -> bf16 d-major UB2[tensor][bh][d][l].  grid (12, 16), 256 thr.
// ---------------------------------------------------------------------------
__global__ __launch_bounds__(256) void k_qkv_mfma(
    const unsigned short* __restrict__ xb, const unsigned short* __restrict__ wT,
    const float* __restrict__ bq, const float* __restrict__ bk,
    const float* __restrict__ bv,
    float* __restrict__ qo, unsigned short* __restrict__ ub2)
{
    const int tid = threadIdx.x;
    const int lane = tid & 63, wave = tid >> 6;
    const int q = lane >> 4, ln = lane & 15;
    const int wm = (wave >> 1) * 64, wn = (wave & 1) * 64;
    const int m0 = blockIdx.y * 128;
    const int n0 = blockIdx.x * 128;

    __shared__ unsigned short As[128*40];
    __shared__ unsigned short Bs[128*40];

    floatx4 acc[4][4];
    #pragma unroll
    for (int i = 0; i < 4; ++i)
        #pragma unroll
        for (int j = 0; j < 4; ++j)
            acc[i][j] = (floatx4){0.f, 0.f, 0.f, 0.f};

    const uint4* Ag = (const uint4*)xb;
    const uint4* Bg = (const uint4*)wT;
    for (int k0 = 0; k0 < 512; k0 += 32) {
        #pragma unroll
        for (int s = 0; s < 2; ++s) {
            int c = tid*2 + s;
            int r = c >> 2, cp = c & 3;
            uint4 va = Ag[(size_t)(m0 + r)*64 + (k0 >> 3) + cp];
            uint4 vb = Bg[(size_t)(n0 + r)*64 + (k0 >> 3) + cp];
            *(uint4*)&As[r*40 + cp*8] = va;
            *(uint4*)&Bs[r*40 + cp*8] = vb;
        }
        __syncthreads();
        short8 af[4], bfr[4];
        #pragma unroll
        for (int i = 0; i < 4; ++i) {
            af[i]  = *(const short8*)&As[(wm + i*16 + ln)*40 + q*8];
            bfr[i] = *(const short8*)&Bs[(wn + i*16 + ln)*40 + q*8];
        }
        #pragma unroll
        for (int mi = 0; mi < 4; ++mi)
            #pragma unroll
            for (int ni = 0; ni < 4; ++ni)
                acc[mi][ni] = __builtin_amdgcn_mfma_f32_16x16x32_bf16(
                    af[mi], bfr[ni], acc[mi][ni], 0, 0, 0);
        __syncthreads();
    }

    const int z = n0 >> 9;
    if (z == 0) {
        #pragma unroll
        for (int mi = 0; mi < 4; ++mi) {
            #pragma unroll
            for (int ni = 0; ni < 4; ++ni) {
                int gcol = n0 + wn + ni*16 + ln;
                int c = gcol & 511;
                int head = c >> 6, dd = c & 63;
                float bb = bq[c];
                #pragma unroll
                for (int reg = 0; reg < 4; ++reg) {
                    int row = m0 + wm + mi*16 + q*4 + reg;
                    int b = row >> 10, l = row & 1023;
                    qo[(size_t)((b*8 + head)*1024 + l)*64 + dd] =
                        acc[mi][ni][reg] + bb;
                }
            }
        }
    } else {
        const float scale = (z == 1) ? 0.125f : 1.0f;
        const float* bias = (z == 1) ? bk : bv;
        unsigned short* dst = ub2 + (size_t)(z-1) * 16 * 64 * 1024;
        #pragma unroll
        for (int mi = 0; mi < 4; ++mi) {
            #pragma unroll
            for (int ni = 0; ni < 4; ++ni) {
                int gcol = n0 + wn + ni*16 + ln;
                int c = gcol & 511;
                int head = c >> 6, dd = c & 63;
                float bb = bias[c];
                int row0 = m0 + wm + mi*16 + q*4;
                int b = row0 >> 10, l0 = row0 & 1023;
                ushort4 o;
                o.x = f2bf((acc[mi][ni][0] + bb) * scale);
                o.y = f2bf((acc[mi][ni][1] + bb) * scale);
                o.z = f2bf((acc[mi][ni][2] + bb) * scale);
                o.w = f2bf((acc[mi][ni][3] + bb) * scale);
                *(ushort4*)&dst[((size_t)((b*8 + head)*64) + dd)*1024 + l0] = o;
            }
        }
    }
}

// ---------------------------------------------------------------------------
// K2: conv as Toeplitz GEMM via MFMA, no LDS, no barriers.
// grid (32 bht, 16 tTiles), 256 thr = 4 waves; wave w owns rows
// [t0+w*16, t0+w*16+16) x 64 cols, K-loop over s<t0+64 streaming frags from L2.
// ---------------------------------------------------------------------------
__global__ __launch_bounds__(256) void k_conv_mfma(
    const unsigned short* __restrict__ TB,
    const unsigned short* __restrict__ ub2,
    float* __restrict__ kc, float* __restrict__ vc)
{
    const int tid = threadIdx.x;
    const int lane = tid & 63, wave = tid >> 6;
    const int q = lane >> 4, ln = lane & 15;
    const int bht = blockIdx.x;
    const int it  = blockIdx.y;
    const int t0  = it * 64;
    const int bh  = bht & 15, h = bh & 7, tensor = bht >> 4;

    const unsigned short* Arow =
        TB + ((size_t)h * 1024 + (t0 + wave*16 + ln)) * 1024;
    const unsigned short* Ub =
        ub2 + (size_t)(tensor*16 + bh) * 64 * 1024;
    float* dst = (tensor ? vc : kc) + (size_t)bh * 65536;

    floatx4 acc[4];
    #pragma unroll
    for (int i = 0; i < 4; ++i) acc[i] = (floatx4){0.f, 0.f, 0.f, 0.f};

    const int kend = t0 + 64;
    // preload step 0
    short8 a = *(const short8*)&Arow[q*8];
    short8 b0 = *(const short8*)&Ub[(size_t)(0*16 + ln)*1024 + q*8];
    short8 b1 = *(const short8*)&Ub[(size_t)(1*16 + ln)*1024 + q*8];
    short8 b2 = *(const short8*)&Ub[(size_t)(2*16 + ln)*1024 + q*8];
    short8 b3 = *(const short8*)&Ub[(size_t)(3*16 + ln)*1024 + q*8];
    for (int s0 = 32; s0 < kend; s0 += 32) {
        short8 an  = *(const short8*)&Arow[s0 + q*8];
        short8 bn0 = *(const short8*)&Ub[(size_t)(0*16 + ln)*1024 + s0 + q*8];
        short8 bn1 = *(const short8*)&Ub[(size_t)(1*16 + ln)*1024 + s0 + q*8];
        short8 bn2 = *(const short8*)&Ub[(size_t)(2*16 + ln)*1024 + s0 + q*8];
        short8 bn3 = *(const short8*)&Ub[(size_t)(3*16 + ln)*1024 + s0 + q*8];
        acc[0] = __builtin_amdgcn_mfma_f32_16x16x32_bf16(a, b0, acc[0], 0, 0, 0);
        acc[1] = __builtin_amdgcn_mfma_f32_16x16x32_bf16(a, b1, acc[1], 0, 0, 0);
        acc[2] = __builtin_amdgcn_mfma_f32_16x16x32_bf16(a, b2, acc[2], 0, 0, 0);
        acc[3] = __builtin_amdgcn_mfma_f32_16x16x32_bf16(a, b3, acc[3], 0, 0, 0);
        a = an; b0 = bn0; b1 = bn1; b2 = bn2; b3 = bn3;
    }
    acc[0] = __builtin_amdgcn_mfma_f32_16x16x32_bf16(a, b0, acc[0], 0, 0, 0);
    acc[1] = __builtin_amdgcn_mfma_f32_16x16x32_bf16(a, b1, acc[1], 0, 0, 0);
    acc[2] = __builtin_amdgcn_mfma_f32_16x16x32_bf16(a, b2, acc[2], 0, 0, 0);
    acc[3] = __builtin_amdgcn_mfma_f32_16x16x32_bf16(a, b3, acc[3], 0, 0, 0);

    #pragma unroll
    for (int ni = 0; ni < 4; ++ni)
        #pragma unroll
        for (int reg = 0; reg < 4; ++reg)
            dst[(size_t)(t0 + wave*16 + q*4 + reg)*64 + ni*16 + ln] =
                acc[ni][reg];
}

// ---------------------------------------------------------------------------
// K3: gate values.  grid (16 lTiles, 16 bh), 256 thr.
// ---------------------------------------------------------------------------
__global__ __launch_bounds__(256) void k_gate(
    const float* __restrict__ kc, const float* __restrict__ vc,
    const float* __restrict__ wg_w, const float* __restrict__ wg_b,
    float* __restrict__ gl)
{
    const int tid = threadIdx.x, tx = tid & 15, ty = tid >> 4;
    const int l0 = blockIdx.x * 64;
    const int bh = blockIdx.y;
    const float* kb = kc + (size_t)bh * 65536;
    const float* vb = vc + (size_t)bh * 65536;

    __shared__ float ks[64][17];
    __shared__ __align__(16) float wsh[16][68];
    float acc[4][4] = {};
    const float4* k4 = (const float4*)kb;
    for (int n0 = 0; n0 < 64; n0 += 16) {
        {
            int r = tid >> 2, c4 = tid & 3;
            float4 t = k4[(size_t)(l0 + r) * 16 + (n0 >> 2) + c4];
            ks[r][c4*4+0]=t.x; ks[r][c4*4+1]=t.y; ks[r][c4*4+2]=t.z; ks[r][c4*4+3]=t.w;
        }
        for (int i = tid; i < 1024; i += 256) {
            int r = i >> 6, c = i & 63;
            wsh[r][c] = wg_w[c*64 + n0 + r];
        }
        __syncthreads();
        #pragma unroll
        for (int kk = 0; kk < 16; ++kk) {
            float a[4];
            a[0] = ks[ty*4+0][kk]; a[1] = ks[ty*4+1][kk];
            a[2] = ks[ty*4+2][kk]; a[3] = ks[ty*4+3][kk];
            float4 b4 = *(const float4*)&wsh[kk][tx*4];
            float bb[4] = {b4.x, b4.y, b4.z, b4.w};
            #pragma unroll
            for (int ii = 0; ii < 4; ++ii)
                #pragma unroll
                for (int jj = 0; jj < 4; ++jj)
                    acc[ii][jj] += a[ii] * bb[jj];
        }
        __syncthreads();
    }
    __shared__ float red[64][17];
    const float wgb = wg_b[0];
    const float4* v4p = (const float4*)vb;
    #pragma unroll
    for (int i = 0; i < 4; ++i) {
        int lr = ty*4 + i;
        float4 vv = v4p[(size_t)(l0 + lr) * 16 + tx];
        red[lr][tx] = acc[i][0]*vv.x + acc[i][1]*vv.y + acc[i][2]*vv.z + acc[i][3]*vv.w;
    }
    __syncthreads();
    if (tid < 64) {
        float s = 0.0f;
        #pragma unroll
        for (int t = 0; t < 16; ++t) s += red[tid][t];
        float logit = s + wgb;
        float r = fmaxf(logit, 0.0f);
        gl[bh*1024 + l0 + tid] = r*r + 1e-5f;
    }
}

// ---------------------------------------------------------------------------
// K4: scans.  One block per bh, 256 thr x 4 elems.
// ---------------------------------------------------------------------------
__global__ __launch_bounds__(256) void k_scan(
    const float* __restrict__ gl, float* __restrict__ wgt)
{
    const int tid = threadIdx.x, bh = blockIdx.x;
    __shared__ float sbuf[256];
    const float4 g4 = ((const float4*)(gl + bh*1024))[tid];
    float g[4] = {g4.x, g4.y, g4.z, g4.w};
    float p[4];
    p[0]=g[0]; p[1]=p[0]+g[1]; p[2]=p[1]+g[2]; p[3]=p[2]+g[3];
    const float s = p[3];
    sbuf[tid] = s;
    __syncthreads();
    for (int off = 1; off < 256; off <<= 1) {
        float t = (tid >= off) ? sbuf[tid-off] : 0.0f;
        __syncthreads();
        sbuf[tid] += t;
        __syncthreads();
    }
    const float base = sbuf[tid] - s;
    float r[4], pr[4];
    #pragma unroll
    for (int u = 0; u < 4; ++u) r[u] = 1.0f / (base + p[u] + 1e-5f);
    pr[0]=r[0]; pr[1]=pr[0]+r[1]; pr[2]=pr[1]+r[2]; pr[3]=pr[2]+r[3];
    const float sr = pr[3];
    __syncthreads();
    sbuf[tid] = sr;
    __syncthreads();
    for (int off = 1; off < 256; off <<= 1) {
        float t = (tid >= off) ? sbuf[tid-off] : 0.0f;
        __syncthreads();
        sbuf[tid] += t;
        __syncthreads();
    }
    const float Rtot  = sbuf[255];
    const float baser = sbuf[tid] - sr;
    float4 o;
    o.x = g[0] * (Rtot - (baser + pr[0]) + r[0]);
    o.y = g[1] * (Rtot - (baser + pr[1]) + r[1]);
    o.z = g[2] * (Rtot - (baser + pr[2]) + r[2]);
    o.w = g[3] * (Rtot - (baser + pr[3]) + r[3]);
    ((float4*)(wgt + bh*1024))[tid] = o;
}

// ---------------------------------------------------------------------------
// K5: A_part[slc][bh] = sum_{j in slice} w_j * outer(v_conv[j], k_conv[j]).
// grid (16 bh, 4 slices), 256 thr.
// ---------------------------------------------------------------------------
__global__ __launch_bounds__(256) void k_amat(
    const float* __restrict__ kc, const float* __restrict__ vc,
    const float* __restrict__ wgt, float* __restrict__ apart)
{
    const int tid = threadIdx.x, tx = tid & 15, ty = tid >> 4;
    const int bh = blockIdx.x, slc = blockIdx.y;
    const float* kb = kc + (size_t)bh * 65536;
    const float* vb = vc + (size_t)bh * 65536;
    const float* wb = wgt + bh*1024;

    __shared__ __align__(16) float vs[16][68];
    __shared__ __align__(16) float ks2[16][68];
    __shared__ float ww[16];
    float acc[4][4] = {};
    const float4* k4 = (const float4*)kb;
    const float4* v4 = (const float4*)vb;
    for (int j0 = slc*256; j0 < slc*256 + 256; j0 += 16) {
        if (tid < 16) ww[tid] = wb[j0 + tid];
        {
            int r = tid >> 4, c4 = tid & 15;
            *(float4*)&vs[r][c4*4]  = v4[(size_t)(j0 + r)*16 + c4];
            *(float4*)&ks2[r][c4*4] = k4[(size_t)(j0 + r)*16 + c4];
        }
        __syncthreads();
        #pragma unroll
        for (int jj = 0; jj < 16; ++jj) {
            float wj = ww[jj];
            float a[4];
            a[0] = vs[jj][ty*4+0]*wj; a[1] = vs[jj][ty*4+1]*wj;
            a[2] = vs[jj][ty*4+2]*wj; a[3] = vs[jj][ty*4+3]*wj;
            float4 b4 = *(const float4*)&ks2[jj][tx*4];
            float bb[4] = {b4.x, b4.y, b4.z, b4.w};
            #pragma unroll
            for (int ii = 0; ii < 4; ++ii)
                #pragma unroll
                for (int jc = 0; jc < 4; ++jc)
                    acc[ii][jc] += a[ii] * bb[jc];
        }
        __syncthreads();
    }
    float* ap = apart + (size_t)(slc*16 + bh) * 4096;
    #pragma unroll
    for (int i = 0; i < 4; ++i) {
        float4 o = { acc[i][0], acc[i][1], acc[i][2], acc[i][3] };
        *(float4*)&ap[(ty*4+i)*64 + tx*4] = o;
    }
}

// ---------------------------------------------------------------------------
// K6: ctxt = q @ A (summing the 4 A-partials on load), row-normalize,
// write unit vectors as bf16 into [B,L,D] layout.  grid (16, 16), 256 thr.
// ---------------------------------------------------------------------------
__global__ __launch_bounds__(256) void k_ctxt(
    const float* __restrict__ q, const float* __restrict__ apart,
    unsigned short* __restrict__ ub)
{
    const int tid = threadIdx.x, tx = tid & 15, ty = tid >> 4;
    const int l0 = blockIdx.x * 64;
    const int bh = blockIdx.y;
    const float* qb = q + (size_t)bh * 65536;

    __shared__ float qs[64][17];
    __shared__ __align__(16) float As[16][68];
    float acc[4][4] = {};
    const float4* q4 = (const float4*)qb;
    const float4* a4 = (const float4*)apart;
    for (int d0 = 0; d0 < 64; d0 += 16) {
        {
            int r = tid >> 2, c4 = tid & 3;
            float4 t = q4[(size_t)(l0 + r)*16 + (d0 >> 2) + c4];
            qs[r][c4*4+0]=t.x; qs[r][c4*4+1]=t.y; qs[r][c4*4+2]=t.z; qs[r][c4*4+3]=t.w;
        }
        {
            int r = tid >> 4, c4 = tid & 15;
            size_t o = (size_t)(d0 + r)*16 + c4;
            float4 t0 = a4[(size_t)(0*16 + bh)*1024 + o];
            float4 t1 = a4[(size_t)(1*16 + bh)*1024 + o];
            float4 t2 = a4[(size_t)(2*16 + bh)*1024 + o];
            float4 t3 = a4[(size_t)(3*16 + bh)*1024 + o];
            float4 t;
            t.x = t0.x+t1.x+t2.x+t3.x; t.y = t0.y+t1.y+t2.y+t3.y;
            t.z = t0.z+t1.z+t2.z+t3.z; t.w = t0.w+t1.w+t2.w+t3.w;
            *(float4*)&As[r][c4*4] = t;
        }
        __syncthreads();
        #pragma unroll
        for (int dd = 0; dd < 16; ++dd) {
            float a[4];
            a[0] = qs[ty*4+0][dd]; a[1] = qs[ty*4+1][dd];
            a[2] = qs[ty*4+2][dd]; a[3] = qs[ty*4+3][dd];
            float4 b4 = *(const float4*)&As[dd][tx*4];
            float bb[4] = {b4.x, b4.y, b4.z, b4.w};
            #pragma unroll
            for (int ii = 0; ii < 4; ++ii)
                #pragma unroll
                for (int jj = 0; jj < 4; ++jj)
                    acc[ii][jj] += a[ii] * bb[jj];
        }
        __syncthreads();
    }
    __shared__ float red[64][17];
    __shared__ float nrm[64];
    #pragma unroll
    for (int i = 0; i < 4; ++i) {
        red[ty*4+i][tx] = acc[i][0]*acc[i][0] + acc[i][1]*acc[i][1]
                        + acc[i][2]*acc[i][2] + acc[i][3]*acc[i][3];
    }
    __syncthreads();
    if (tid < 64) {
        float s = 0.0f;
        #pragma unroll
        for (int t = 0; t < 16; ++t) s += red[tid][t];
        nrm[tid] = fmaxf(sqrtf(s), 1e-5f);
    }
    __syncthreads();
    const int b = bh >> 3, hd = bh & 7;
    #pragma unroll
    for (int i = 0; i < 4; ++i) {
        int lr = ty*4 + i;
        float inv = 1.0f / nrm[lr];
        ushort4 o;
        o.x = f2bf(acc[i][0]*inv); o.y = f2bf(acc[i][1]*inv);
        o.z = f2bf(acc[i][2]*inv); o.w = f2bf(acc[i][3]*inv);
        *(ushort4*)&ub[(size_t)(b*1024 + l0 + lr)*512 + hd*64 + tx*4] = o;
    }
}

// ---------------------------------------------------------------------------
// K7: out = Ub[2048][512](bf16) @ woT^T + wo_b via MFMA.  grid (4, 16).
// ---------------------------------------------------------------------------
__global__ __launch_bounds__(256) void k_out_mfma(
    const unsigned short* __restrict__ ub, const unsigned short* __restrict__ woT,
    const float* __restrict__ bo, float* __restrict__ out)
{
    const int tid = threadIdx.x;
    const int lane = tid & 63, wave = tid >> 6;
    const int q = lane >> 4, ln = lane & 15;
    const int wm = (wave >> 1) * 64, wn = (wave & 1) * 64;
    const int m0 = blockIdx.y * 128;
    const int n0 = blockIdx.x * 128;

    __shared__ unsigned short As[128*40];
    __shared__ unsigned short Bs[128*40];

    floatx4 acc[4][4];
    #pragma unroll
    for (int i = 0; i < 4; ++i)
        #pragma unroll
        for (int j = 0; j < 4; ++j)
            acc[i][j] = (floatx4){0.f, 0.f, 0.f, 0.f};

    const uint4* Ag = (const uint4*)ub;
    const uint4* Bg = (const uint4*)woT;
    for (int k0 = 0; k0 < 512; k0 += 32) {
        #pragma unroll
        for (int s = 0; s < 2; ++s) {
            int c = tid*2 + s;
            int r = c >> 2, cp = c & 3;
            uint4 va = Ag[(size_t)(m0 + r)*64 + (k0 >> 3) + cp];
            uint4 vb = Bg[(size_t)(n0 + r)*64 + (k0 >> 3) + cp];
            *(uint4*)&As[r*40 + cp*8] = va;
            *(uint4*)&Bs[r*40 + cp*8] = vb;
        }
        __syncthreads();
        short8 af[4], bfr[4];
        #pragma unroll
        for (int i = 0; i < 4; ++i) {
            af[i]  = *(const short8*)&As[(wm + i*16 + ln)*40 + q*8];
            bfr[i] = *(const short8*)&Bs[(wn + i*16 + ln)*40 + q*8];
        }
        #pragma unroll
        for (int mi = 0; mi < 4; ++mi)
            #pragma unroll
            for (int ni = 0; ni < 4; ++ni)
                acc[mi][ni] = __builtin_amdgcn_mfma_f32_16x16x32_bf16(
                    af[mi], bfr[ni], acc[mi][ni], 0, 0, 0);
        __syncthreads();
    }

    #pragma unroll
    for (int mi = 0; mi < 4; ++mi) {
        #pragma unroll
        for (int ni = 0; ni < 4; ++ni) {
            int gcol = n0 + wn + ni*16 + ln;
            float bb = bo[gcol];
            #pragma unroll
            for (int reg = 0; reg < 4; ++reg) {
                int row = m0 + wm + mi*16 + q*4 + reg;
                out[(size_t)row*512 + gcol] = acc[mi][ni][reg] + bb;
            }
        }
    }
}

extern "C" void kernel_launch(void* const* d_in, const int* in_sizes, int n_in,
                              void* d_out, int out_size, void* d_ws, size_t ws_size,
                              hipStream_t stream)
{
    const float* x   = (const float*)d_in[0];
    const float* sb  = (const float*)d_in[1];
    const float* wq  = (const float*)d_in[2];
    const float* bq  = (const float*)d_in[3];
    const float* wk  = (const float*)d_in[4];
    const float* bk  = (const float*)d_in[5];
    const float* wv  = (const float*)d_in[6];
    const float* bv  = (const float*)d_in[7];
    const float* wo  = (const float*)d_in[8];
    const float* bo  = (const float*)d_in[9];
    const float* wg  = (const float*)d_in[10];
    const float* wgb = (const float*)d_in[11];
    float* out = (float*)d_out;
    float* ws  = (float*)d_ws;

    // workspace layout (float offsets)
    float* Q   = ws;                        // 1048576  [B,H,L,64] fp32
    float* KC  = ws + 1048576;              // 1048576  k_conv fp32
    float* VC  = ws + 2*1048576;            // 1048576  v_conv fp32
    float* GL  = ws + 3*1048576;            // 16384
    float* WGT = GL + 16384;                // 16384
    float* AP  = WGT + 16384;               // 262144
    float* fp  = AP + 262144;
    unsigned short* XB  = (unsigned short*)fp;              // 2048*512 bf16
    unsigned short* WT  = XB  + 1048576;                    // 1536*512 bf16
    unsigned short* WOT = WT  + 786432;                     // 512*512 bf16
    unsigned short* UB  = WOT + 262144;                     // 2048*512 bf16
    unsigned short* UB2 = UB  + 1048576;                    // 2*16*64*1024 bf16
    unsigned short* TB  = UB2 + 2097152;                    // 8*1024*1024 bf16

    k_castx    <<<dim3(512),     256, 0, stream>>>(x, XB);
    k_packw    <<<dim3(256),     256, 0, stream>>>(wq, wk, wv, wo, WT, WOT);
    k_mkT      <<<dim3(8, 32),   256, 0, stream>>>(sb, TB);
    k_qkv_mfma <<<dim3(12, 16),  256, 0, stream>>>(XB, WT, bq, bk, bv, Q, UB2);
    k_conv_mfma<<<dim3(32, 16),  256, 0, stream>>>(TB, UB2, KC, VC);
    k_gate     <<<dim3(16, 16),  256, 0, stream>>>(KC, VC, wg, wgb, GL);
    k_scan     <<<dim3(16),      256, 0, stream>>>(GL, WGT);
    k_amat     <<<dim3(16, 4),   256, 0, stream>>>(KC, VC, WGT, AP);
    k_ctxt     <<<dim3(16, 16),  256, 0, stream>>>(Q, AP, UB);
    k_out_mfma <<<dim3(4, 16),   256, 0, stream>>>(UB, WOT, bo, out);
}

// Round 6
// 186.858 us; speedup vs baseline: 1.8247x; 1.0184x over previous
//
#include <hip/hip_runtime.h>
#include <math.h>

// Problem constants: B=2, L=1024, D=512, H=8, h=64, K=H=8, EPS=1e-5
// Layouts: q/kc/vc stored as [B*H][L][64] (bh*65536 + l*64 + d)
// UB2: bf16 conv inputs, d-major [tensor][bh][d=64][l=1024]
// TB:  bf16 Toeplitz filters [h=8][t=1024][s=1024], zero above diagonal

typedef __attribute__((ext_vector_type(8))) short short8;
typedef __attribute__((ext_vector_type(4))) float floatx4;

__device__ __forceinline__ unsigned short f2bf(float f) {
    unsigned int u = __float_as_uint(f);
    unsigned int r = (u + 0x7FFFu + ((u >> 16) & 1u)) >> 16;   // RNE
    return (unsigned short)r;
}

// ---------------------------------------------------------------------------
// K0: fused prep.  blocks 0-511: cast x -> bf16.  512-767: transpose+cast
// weights.  768-1023: materialize Toeplitz filters TB[h][t][s].
// ---------------------------------------------------------------------------
__global__ __launch_bounds__(256) void k_prep(
    const float* __restrict__ x,
    const float* __restrict__ wq, const float* __restrict__ wk,
    const float* __restrict__ wv, const float* __restrict__ wo,
    const float* __restrict__ sb,
    unsigned short* __restrict__ xb,
    unsigned short* __restrict__ wT, unsigned short* __restrict__ woT,
    unsigned short* __restrict__ TB)
{
    __shared__ float sf[64][65];
    const int blk = blockIdx.x;
    const int tid = threadIdx.x;

    if (blk < 512) {                       // ---- castx ----
        const int gid = blk * 256 + tid;
        const float4* x4 = (const float4*)x;
        float4 a = x4[gid*2], b = x4[gid*2+1];
        uint4 o;
        o.x = f2bf(a.x) | ((unsigned)f2bf(a.y) << 16);
        o.y = f2bf(a.z) | ((unsigned)f2bf(a.w) << 16);
        o.z = f2bf(b.x) | ((unsigned)f2bf(b.y) << 16);
        o.w = f2bf(b.z) | ((unsigned)f2bf(b.w) << 16);
        ((uint4*)xb)[gid] = o;
    } else if (blk < 768) {                // ---- packw ----
        const int t = blk - 512;
        const float* src; unsigned short* dst; int n0, c0, k0;
        if (t < 192) {
            int nt = t >> 3, kt = t & 7;
            n0 = nt * 64; k0 = kt * 64;
            int z = n0 >> 9; c0 = n0 & 511;
            src = (z == 0) ? wq : (z == 1) ? wk : wv;
            dst = wT;
        } else {
            int u = t - 192; int nt = u >> 3, kt = u & 7;
            n0 = nt * 64; c0 = n0; k0 = kt * 64;
            src = wo; dst = woT;
        }
        const int rr = tid >> 4, c4 = tid & 15;
        #pragma unroll
        for (int g = 0; g < 4; ++g) {
            int r = g*16 + rr;
            float4 v = *(const float4*)&src[(size_t)(k0 + r)*512 + c0 + c4*4];
            sf[r][c4*4+0]=v.x; sf[r][c4*4+1]=v.y; sf[r][c4*4+2]=v.z; sf[r][c4*4+3]=v.w;
        }
        __syncthreads();
        #pragma unroll
        for (int g = 0; g < 4; ++g) {
            int c = g*16 + rr;
            int kk = c4*4;
            ushort4 o;
            o.x = f2bf(sf[kk+0][c]); o.y = f2bf(sf[kk+1][c]);
            o.z = f2bf(sf[kk+2][c]); o.w = f2bf(sf[kk+3][c]);
            *(ushort4*)&dst[(size_t)(n0 + c)*512 + k0 + kk] = o;
        }
    } else {                               // ---- mkT ----
        const int u = blk - 768;
        const int h = u >> 5;
        const int r0 = (u & 31) * 32;
        unsigned short* sbc = (unsigned short*)sf;     // 1024 ushorts
        for (int i = tid; i < 1024; i += 256)
            sbc[i] = f2bf(sb[i*8 + h]);
        __syncthreads();
        const int rr = tid >> 3, c0 = (tid & 7) * 128;
        const int t = r0 + rr;
        unsigned short* row = TB + ((size_t)h * 1024 + t) * 1024;
        for (int c = c0; c < c0 + 128; c += 8) {
            unsigned short v[8];
            #pragma unroll
            for (int j = 0; j < 8; ++j) {
                int s = c + j;
                v[j] = (t >= s) ? sbc[t - s] : (unsigned short)0;
            }
            uint4 o;
            o.x = v[0] | ((unsigned)v[1]<<16);
            o.y = v[2] | ((unsigned)v[3]<<16);
            o.z = v[4] | ((unsigned)v[5]<<16);
            o.w = v[6] | ((unsigned)v[7]<<16);
            *(uint4*)&row[c] = o;
        }
    }
}

// ---------------------------------------------------------------------------
// K1: QKV projection via MFMA.  C[2048][1536] = xb @ wT^T.  q -> fp32 [bh][l][64];
// k (scaled), v -> bf16 d-major UB2[tensor][bh][d][l].  grid (12, 16), 256 thr.
// ---------------------------------------------------------------------------
__global__ __launch_bounds__(256) void k_qkv_mfma(
    const unsigned short* __restrict__ xb, const unsigned short* __restrict__ wT,
    const float* __restrict__ bq, const float* __restrict__ bk,
    const float* __restrict__ bv,
    float* __restrict__ qo, unsigned short* __restrict__ ub2)
{
    const int tid = threadIdx.x;
    const int lane = tid & 63, wave = tid >> 6;
    const int q = lane >> 4, ln = lane & 15;
    const int wm = (wave >> 1) * 64, wn = (wave & 1) * 64;
    const int m0 = blockIdx.y * 128;
    const int n0 = blockIdx.x * 128;

    __shared__ unsigned short As[128*40];
    __shared__ unsigned short Bs[128*40];

    floatx4 acc[4][4];
    #pragma unroll
    for (int i = 0; i < 4; ++i)
        #pragma unroll
        for (int j = 0; j < 4; ++j)
            acc[i][j] = (floatx4){0.f, 0.f, 0.f, 0.f};

    const uint4* Ag = (const uint4*)xb;
    const uint4* Bg = (const uint4*)wT;
    for (int k0 = 0; k0 < 512; k0 += 32) {
        #pragma unroll
        for (int s = 0; s < 2; ++s) {
            int c = tid*2 + s;
            int r = c >> 2, cp = c & 3;
            uint4 va = Ag[(size_t)(m0 + r)*64 + (k0 >> 3) + cp];
            uint4 vb = Bg[(size_t)(n0 + r)*64 + (k0 >> 3) + cp];
            *(uint4*)&As[r*40 + cp*8] = va;
            *(uint4*)&Bs[r*40 + cp*8] = vb;
        }
        __syncthreads();
        short8 af[4], bfr[4];
        #pragma unroll
        for (int i = 0; i < 4; ++i) {
            af[i]  = *(const short8*)&As[(wm + i*16 + ln)*40 + q*8];
            bfr[i] = *(const short8*)&Bs[(wn + i*16 + ln)*40 + q*8];
        }
        #pragma unroll
        for (int mi = 0; mi < 4; ++mi)
            #pragma unroll
            for (int ni = 0; ni < 4; ++ni)
                acc[mi][ni] = __builtin_amdgcn_mfma_f32_16x16x32_bf16(
                    af[mi], bfr[ni], acc[mi][ni], 0, 0, 0);
        __syncthreads();
    }

    const int z = n0 >> 9;
    if (z == 0) {
        #pragma unroll
        for (int mi = 0; mi < 4; ++mi) {
            #pragma unroll
            for (int ni = 0; ni < 4; ++ni) {
                int gcol = n0 + wn + ni*16 + ln;
                int c = gcol & 511;
                int head = c >> 6, dd = c & 63;
                float bb = bq[c];
                #pragma unroll
                for (int reg = 0; reg < 4; ++reg) {
                    int row = m0 + wm + mi*16 + q*4 + reg;
                    int b = row >> 10, l = row & 1023;
                    qo[(size_t)((b*8 + head)*1024 + l)*64 + dd] =
                        acc[mi][ni][reg] + bb;
                }
            }
        }
    } else {
        const float scale = (z == 1) ? 0.125f : 1.0f;
        const float* bias = (z == 1) ? bk : bv;
        unsigned short* dst = ub2 + (size_t)(z-1) * 16 * 64 * 1024;
        #pragma unroll
        for (int mi = 0; mi < 4; ++mi) {
            #pragma unroll
            for (int ni = 0; ni < 4; ++ni) {
                int gcol = n0 + wn + ni*16 + ln;
                int c = gcol & 511;
                int head = c >> 6, dd = c & 63;
                float bb = bias[c];
                int row0 = m0 + wm + mi*16 + q*4;
                int b = row0 >> 10, l0 = row0 & 1023;
                ushort4 o;
                o.x = f2bf((acc[mi][ni][0] + bb) * scale);
                o.y = f2bf((acc[mi][ni][1] + bb) * scale);
                o.z = f2bf((acc[mi][ni][2] + bb) * scale);
                o.w = f2bf((acc[mi][ni][3] + bb) * scale);
                *(ushort4*)&dst[((size_t)((b*8 + head)*64) + dd)*1024 + l0] = o;
            }
        }
    }
}

// ---------------------------------------------------------------------------
// K2: conv as Toeplitz GEMM via MFMA, no LDS, no barriers.
// grid (32 bht, 16 tTiles, 2 colHalves), 256 thr = 4 waves; wave w owns rows
// [t0+w*16, +16) x 32 cols; K-unroll 64 with manual prefetch (6 loads/iter
// in flight, 4 MFMAs/iter).  4096 waves = 4/SIMD.
// ---------------------------------------------------------------------------
__global__ __launch_bounds__(256) void k_conv_mfma(
    const unsigned short* __restrict__ TB,
    const unsigned short* __restrict__ ub2,
    float* __restrict__ kc, float* __restrict__ vc)
{
    const int tid = threadIdx.x;
    const int lane = tid & 63, wave = tid >> 6;
    const int q = lane >> 4, ln = lane & 15;
    const int bht = blockIdx.x;
    const int it  = blockIdx.y;
    const int d0  = blockIdx.z * 32;
    const int t0  = it * 64;
    const int bh  = bht & 15, h = bh & 7, tensor = bht >> 4;

    const unsigned short* Arow =
        TB + ((size_t)h * 1024 + (t0 + wave*16 + ln)) * 1024;
    const unsigned short* B0 =
        ub2 + (size_t)(tensor*16 + bh) * 64 * 1024 + (size_t)(d0 + ln) * 1024;
    const unsigned short* B1 = B0 + 16 * 1024;
    float* dst = (tensor ? vc : kc) + (size_t)bh * 65536;

    floatx4 acc0 = (floatx4){0.f,0.f,0.f,0.f};
    floatx4 acc1 = (floatx4){0.f,0.f,0.f,0.f};

    const int kend = t0 + 64;
    const int q8 = q * 8;
    // preload s0 = 0
    short8 a0  = *(const short8*)&Arow[q8];
    short8 a1  = *(const short8*)&Arow[32 + q8];
    short8 b00 = *(const short8*)&B0[q8];
    short8 b01 = *(const short8*)&B0[32 + q8];
    short8 b10 = *(const short8*)&B1[q8];
    short8 b11 = *(const short8*)&B1[32 + q8];
    for (int s0 = 64; s0 < kend; s0 += 64) {
        short8 na0  = *(const short8*)&Arow[s0 + q8];
        short8 na1  = *(const short8*)&Arow[s0 + 32 + q8];
        short8 nb00 = *(const short8*)&B0[s0 + q8];
        short8 nb01 = *(const short8*)&B0[s0 + 32 + q8];
        short8 nb10 = *(const short8*)&B1[s0 + q8];
        short8 nb11 = *(const short8*)&B1[s0 + 32 + q8];
        acc0 = __builtin_amdgcn_mfma_f32_16x16x32_bf16(a0, b00, acc0, 0, 0, 0);
        acc0 = __builtin_amdgcn_mfma_f32_16x16x32_bf16(a1, b01, acc0, 0, 0, 0);
        acc1 = __builtin_amdgcn_mfma_f32_16x16x32_bf16(a0, b10, acc1, 0, 0, 0);
        acc1 = __builtin_amdgcn_mfma_f32_16x16x32_bf16(a1, b11, acc1, 0, 0, 0);
        a0 = na0; a1 = na1; b00 = nb00; b01 = nb01; b10 = nb10; b11 = nb11;
    }
    acc0 = __builtin_amdgcn_mfma_f32_16x16x32_bf16(a0, b00, acc0, 0, 0, 0);
    acc0 = __builtin_amdgcn_mfma_f32_16x16x32_bf16(a1, b01, acc0, 0, 0, 0);
    acc1 = __builtin_amdgcn_mfma_f32_16x16x32_bf16(a0, b10, acc1, 0, 0, 0);
    acc1 = __builtin_amdgcn_mfma_f32_16x16x32_bf16(a1, b11, acc1, 0, 0, 0);

    #pragma unroll
    for (int reg = 0; reg < 4; ++reg) {
        int row = t0 + wave*16 + q*4 + reg;
        dst[(size_t)row*64 + d0 + ln]      = acc0[reg];
        dst[(size_t)row*64 + d0 + 16 + ln] = acc1[reg];
    }
}

// ---------------------------------------------------------------------------
// K3: gate values.  grid (16 lTiles, 16 bh), 256 thr.
// ---------------------------------------------------------------------------
__global__ __launch_bounds__(256) void k_gate(
    const float* __restrict__ kc, const float* __restrict__ vc,
    const float* __restrict__ wg_w, const float* __restrict__ wg_b,
    float* __restrict__ gl)
{
    const int tid = threadIdx.x, tx = tid & 15, ty = tid >> 4;
    const int l0 = blockIdx.x * 64;
    const int bh = blockIdx.y;
    const float* kb = kc + (size_t)bh * 65536;
    const float* vb = vc + (size_t)bh * 65536;

    __shared__ float ks[64][17];
    __shared__ __align__(16) float wsh[16][68];
    float acc[4][4] = {};
    const float4* k4 = (const float4*)kb;
    for (int n0 = 0; n0 < 64; n0 += 16) {
        {
            int r = tid >> 2, c4 = tid & 3;
            float4 t = k4[(size_t)(l0 + r) * 16 + (n0 >> 2) + c4];
            ks[r][c4*4+0]=t.x; ks[r][c4*4+1]=t.y; ks[r][c4*4+2]=t.z; ks[r][c4*4+3]=t.w;
        }
        for (int i = tid; i < 1024; i += 256) {
            int r = i >> 6, c = i & 63;
            wsh[r][c] = wg_w[c*64 + n0 + r];
        }
        __syncthreads();
        #pragma unroll
        for (int kk = 0; kk < 16; ++kk) {
            float a[4];
            a[0] = ks[ty*4+0][kk]; a[1] = ks[ty*4+1][kk];
            a[2] = ks[ty*4+2][kk]; a[3] = ks[ty*4+3][kk];
            float4 b4 = *(const float4*)&wsh[kk][tx*4];
            float bb[4] = {b4.x, b4.y, b4.z, b4.w};
            #pragma unroll
            for (int ii = 0; ii < 4; ++ii)
                #pragma unroll
                for (int jj = 0; jj < 4; ++jj)
                    acc[ii][jj] += a[ii] * bb[jj];
        }
        __syncthreads();
    }
    __shared__ float red[64][17];
    const float wgb = wg_b[0];
    const float4* v4p = (const float4*)vb;
    #pragma unroll
    for (int i = 0; i < 4; ++i) {
        int lr = ty*4 + i;
        float4 vv = v4p[(size_t)(l0 + lr) * 16 + tx];
        red[lr][tx] = acc[i][0]*vv.x + acc[i][1]*vv.y + acc[i][2]*vv.z + acc[i][3]*vv.w;
    }
    __syncthreads();
    if (tid < 64) {
        float s = 0.0f;
        #pragma unroll
        for (int t = 0; t < 16; ++t) s += red[tid][t];
        float logit = s + wgb;
        float r = fmaxf(logit, 0.0f);
        gl[bh*1024 + l0 + tid] = r*r + 1e-5f;
    }
}

// ---------------------------------------------------------------------------
// K5: A_part[slc][bh] = sum_{j in slice} w_j * outer(v_conv[j], k_conv[j]),
// with the gate scan (w_j = g_j * suffix(1/prefix(g))) computed inline.
// grid (16 bh, 4 slices), 256 thr.
// ---------------------------------------------------------------------------
__global__ __launch_bounds__(256) void k_amat(
    const float* __restrict__ kc, const float* __restrict__ vc,
    const float* __restrict__ gl, float* __restrict__ apart)
{
    const int tid = threadIdx.x, tx = tid & 15, ty = tid >> 4;
    const int bh = blockIdx.x, slc = blockIdx.y;
    const float* kb = kc + (size_t)bh * 65536;
    const float* vb = vc + (size_t)bh * 65536;

    __shared__ float sbuf[256];
    __shared__ float wfull[1024];
    __shared__ __align__(16) float vs[16][68];
    __shared__ __align__(16) float ks2[16][68];

    // ---- inline scan: wfull[j] = g_j * sum_{l>=j} 1/(G_l + eps) ----
    {
        const float4 g4 = ((const float4*)(gl + bh*1024))[tid];
        float g[4] = {g4.x, g4.y, g4.z, g4.w};
        float p[4];
        p[0]=g[0]; p[1]=p[0]+g[1]; p[2]=p[1]+g[2]; p[3]=p[2]+g[3];
        const float s = p[3];
        sbuf[tid] = s;
        __syncthreads();
        for (int off = 1; off < 256; off <<= 1) {
            float t = (tid >= off) ? sbuf[tid-off] : 0.0f;
            __syncthreads();
            sbuf[tid] += t;
            __syncthreads();
        }
        const float base = sbuf[tid] - s;
        float r[4], pr[4];
        #pragma unroll
        for (int u = 0; u < 4; ++u) r[u] = 1.0f / (base + p[u] + 1e-5f);
        pr[0]=r[0]; pr[1]=pr[0]+r[1]; pr[2]=pr[1]+r[2]; pr[3]=pr[2]+r[3];
        const float sr = pr[3];
        __syncthreads();
        sbuf[tid] = sr;
        __syncthreads();
        for (int off = 1; off < 256; off <<= 1) {
            float t = (tid >= off) ? sbuf[tid-off] : 0.0f;
            __syncthreads();
            sbuf[tid] += t;
            __syncthreads();
        }
        const float Rtot  = sbuf[255];
        const float baser = sbuf[tid] - sr;
        wfull[tid*4+0] = g[0] * (Rtot - (baser + pr[0]) + r[0]);
        wfull[tid*4+1] = g[1] * (Rtot - (baser + pr[1]) + r[1]);
        wfull[tid*4+2] = g[2] * (Rtot - (baser + pr[2]) + r[2]);
        wfull[tid*4+3] = g[3] * (Rtot - (baser + pr[3]) + r[3]);
    }
    __syncthreads();

    float acc[4][4] = {};
    const float4* k4 = (const float4*)kb;
    const float4* v4 = (const float4*)vb;
    for (int j0 = slc*256; j0 < slc*256 + 256; j0 += 16) {
        {
            int r = tid >> 4, c4 = tid & 15;
            *(float4*)&vs[r][c4*4]  = v4[(size_t)(j0 + r)*16 + c4];
            *(float4*)&ks2[r][c4*4] = k4[(size_t)(j0 + r)*16 + c4];
        }
        __syncthreads();
        #pragma unroll
        for (int jj = 0; jj < 16; ++jj) {
            float wj = wfull[j0 + jj];
            float a[4];
            a[0] = vs[jj][ty*4+0]*wj; a[1] = vs[jj][ty*4+1]*wj;
            a[2] = vs[jj][ty*4+2]*wj; a[3] = vs[jj][ty*4+3]*wj;
            float4 b4 = *(const float4*)&ks2[jj][tx*4];
            float bb[4] = {b4.x, b4.y, b4.z, b4.w};
            #pragma unroll
            for (int ii = 0; ii < 4; ++ii)
                #pragma unroll
                for (int jc = 0; jc < 4; ++jc)
                    acc[ii][jc] += a[ii] * bb[jc];
        }
        __syncthreads();
    }
    float* ap = apart + (size_t)(slc*16 + bh) * 4096;
    #pragma unroll
    for (int i = 0; i < 4; ++i) {
        float4 o = { acc[i][0], acc[i][1], acc[i][2], acc[i][3] };
        *(float4*)&ap[(ty*4+i)*64 + tx*4] = o;
    }
}

// ---------------------------------------------------------------------------
// K6: ctxt = q @ A (summing the 4 A-partials on load), row-normalize,
// write unit vectors as bf16 into [B,L,D] layout.  grid (16, 16), 256 thr.
// ---------------------------------------------------------------------------
__global__ __launch_bounds__(256) void k_ctxt(
    const float* __restrict__ q, const float* __restrict__ apart,
    unsigned short* __restrict__ ub)
{
    const int tid = threadIdx.x, tx = tid & 15, ty = tid >> 4;
    const int l0 = blockIdx.x * 64;
    const int bh = blockIdx.y;
    const float* qb = q + (size_t)bh * 65536;

    __shared__ float qs[64][17];
    __shared__ __align__(16) float As[16][68];
    float acc[4][4] = {};
    const float4* q4 = (const float4*)qb;
    const float4* a4 = (const float4*)apart;
    for (int d0 = 0; d0 < 64; d0 += 16) {
        {
            int r = tid >> 2, c4 = tid & 3;
            float4 t = q4[(size_t)(l0 + r)*16 + (d0 >> 2) + c4];
            qs[r][c4*4+0]=t.x; qs[r][c4*4+1]=t.y; qs[r][c4*4+2]=t.z; qs[r][c4*4+3]=t.w;
        }
        {
            int r = tid >> 4, c4 = tid & 15;
            size_t o = (size_t)(d0 + r)*16 + c4;
            float4 t0 = a4[(size_t)(0*16 + bh)*1024 + o];
            float4 t1 = a4[(size_t)(1*16 + bh)*1024 + o];
            float4 t2 = a4[(size_t)(2*16 + bh)*1024 + o];
            float4 t3 = a4[(size_t)(3*16 + bh)*1024 + o];
            float4 t;
            t.x = t0.x+t1.x+t2.x+t3.x; t.y = t0.y+t1.y+t2.y+t3.y;
            t.z = t0.z+t1.z+t2.z+t3.z; t.w = t0.w+t1.w+t2.w+t3.w;
            *(float4*)&As[r][c4*4] = t;
        }
        __syncthreads();
        #pragma unroll
        for (int dd = 0; dd < 16; ++dd) {
            float a[4];
            a[0] = qs[ty*4+0][dd]; a[1] = qs[ty*4+1][dd];
            a[2] = qs[ty*4+2][dd]; a[3] = qs[ty*4+3][dd];
            float4 b4 = *(const float4*)&As[dd][tx*4];
            float bb[4] = {b4.x, b4.y, b4.z, b4.w};
            #pragma unroll
            for (int ii = 0; ii < 4; ++ii)
                #pragma unroll
                for (int jj = 0; jj < 4; ++jj)
                    acc[ii][jj] += a[ii] * bb[jj];
        }
        __syncthreads();
    }
    __shared__ float red[64][17];
    __shared__ float nrm[64];
    #pragma unroll
    for (int i = 0; i < 4; ++i) {
        red[ty*4+i][tx] = acc[i][0]*acc[i][0] + acc[i][1]*acc[i][1]
                        + acc[i][2]*acc[i][2] + acc[i][3]*acc[i][3];
    }
    __syncthreads();
    if (tid < 64) {
        float s = 0.0f;
        #pragma unroll
        for (int t = 0; t < 16; ++t) s += red[tid][t];
        nrm[tid] = fmaxf(sqrtf(s), 1e-5f);
    }
    __syncthreads();
    const int b = bh >> 3, hd = bh & 7;
    #pragma unroll
    for (int i = 0; i < 4; ++i) {
        int lr = ty*4 + i;
        float inv = 1.0f / nrm[lr];
        ushort4 o;
        o.x = f2bf(acc[i][0]*inv); o.y = f2bf(acc[i][1]*inv);
        o.z = f2bf(acc[i][2]*inv); o.w = f2bf(acc[i][3]*inv);
        *(ushort4*)&ub[(size_t)(b*1024 + l0 + lr)*512 + hd*64 + tx*4] = o;
    }
}

// ---------------------------------------------------------------------------
// K7: out = Ub[2048][512](bf16) @ woT^T + wo_b via MFMA.  grid (4, 16).
// ---------------------------------------------------------------------------
__global__ __launch_bounds__(256) void k_out_mfma(
    const unsigned short* __restrict__ ub, const unsigned short* __restrict__ woT,
    const float* __restrict__ bo, float* __restrict__ out)
{
    const int tid = threadIdx.x;
    const int lane = tid & 63, wave = tid >> 6;
    const int q = lane >> 4, ln = lane & 15;
    const int wm = (wave >> 1) * 64, wn = (wave & 1) * 64;
    const int m0 = blockIdx.y * 128;
    const int n0 = blockIdx.x * 128;

    __shared__ unsigned short As[128*40];
    __shared__ unsigned short Bs[128*40];

    floatx4 acc[4][4];
    #pragma unroll
    for (int i = 0; i < 4; ++i)
        #pragma unroll
        for (int j = 0; j < 4; ++j)
            acc[i][j] = (floatx4){0.f, 0.f, 0.f, 0.f};

    const uint4* Ag = (const uint4*)ub;
    const uint4* Bg = (const uint4*)woT;
    for (int k0 = 0; k0 < 512; k0 += 32) {
        #pragma unroll
        for (int s = 0; s < 2; ++s) {
            int c = tid*2 + s;
            int r = c >> 2, cp = c & 3;
            uint4 va = Ag[(size_t)(m0 + r)*64 + (k0 >> 3) + cp];
            uint4 vb = Bg[(size_t)(n0 + r)*64 + (k0 >> 3) + cp];
            *(uint4*)&As[r*40 + cp*8] = va;
            *(uint4*)&Bs[r*40 + cp*8] = vb;
        }
        __syncthreads();
        short8 af[4], bfr[4];
        #pragma unroll
        for (int i = 0; i < 4; ++i) {
            af[i]  = *(const short8*)&As[(wm + i*16 + ln)*40 + q*8];
            bfr[i] = *(const short8*)&Bs[(wn + i*16 + ln)*40 + q*8];
        }
        #pragma unroll
        for (int mi = 0; mi < 4; ++mi)
            #pragma unroll
            for (int ni = 0; ni < 4; ++ni)
                acc[mi][ni] = __builtin_amdgcn_mfma_f32_16x16x32_bf16(
                    af[mi], bfr[ni], acc[mi][ni], 0, 0, 0);
        __syncthreads();
    }

    #pragma unroll
    for (int mi = 0; mi < 4; ++mi) {
        #pragma unroll
        for (int ni = 0; ni < 4; ++ni) {
            int gcol = n0 + wn + ni*16 + ln;
            float bb = bo[gcol];
            #pragma unroll
            for (int reg = 0; reg < 4; ++reg) {
                int row = m0 + wm + mi*16 + q*4 + reg;
                out[(size_t)row*512 + gcol] = acc[mi][ni][reg] + bb;
            }
        }
    }
}

extern "C" void kernel_launch(void* const* d_in, const int* in_sizes, int n_in,
                              void* d_out, int out_size, void* d_ws, size_t ws_size,
                              hipStream_t stream)
{
    const float* x   = (const float*)d_in[0];
    const float* sb  = (const float*)d_in[1];
    const float* wq  = (const float*)d_in[2];
    const float* bq  = (const float*)d_in[3];
    const float* wk  = (const float*)d_in[4];
    const float* bk  = (const float*)d_in[5];
    const float* wv  = (const float*)d_in[6];
    const float* bv  = (const float*)d_in[7];
    const float* wo  = (const float*)d_in[8];
    const float* bo  = (const float*)d_in[9];
    const float* wg  = (const float*)d_in[10];
    const float* wgb = (const float*)d_in[11];
    float* out = (float*)d_out;
    float* ws  = (float*)d_ws;

    // workspace layout (float offsets)
    float* Q   = ws;                        // 1048576  [B,H,L,64] fp32
    float* KC  = ws + 1048576;              // 1048576  k_conv fp32
    float* VC  = ws + 2*1048576;            // 1048576  v_conv fp32
    float* GL  = ws + 3*1048576;            // 16384
    float* AP  = GL + 16384;                // 262144
    float* fp  = AP + 262144;
    unsigned short* XB  = (unsigned short*)fp;              // 2048*512 bf16
    unsigned short* WT  = XB  + 1048576;                    // 1536*512 bf16
    unsigned short* WOT = WT  + 786432;                     // 512*512 bf16
    unsigned short* UB  = WOT + 262144;                     // 2048*512 bf16
    unsigned short* UB2 = UB  + 1048576;                    // 2*16*64*1024 bf16
    unsigned short* TB  = UB2 + 2097152;                    // 8*1024*1024 bf16

    k_prep     <<<dim3(1024),      256, 0, stream>>>(x, wq, wk, wv, wo, sb,
                                                     XB, WT, WOT, TB);
    k_qkv_mfma <<<dim3(12, 16),    256, 0, stream>>>(XB, WT, bq, bk, bv, Q, UB2);
    k_conv_mfma<<<dim3(32, 16, 2), 256, 0, stream>>>(TB, UB2, KC, VC);
    k_gate     <<<dim3(16, 16),    256, 0, stream>>>(KC, VC, wg, wgb, GL);
    k_amat     <<<dim3(16, 4),     256, 0, stream>>>(KC, VC, GL, AP);
    k_ctxt     <<<dim3(16, 16),    256, 0, stream>>>(Q, AP, UB);
    k_out_mfma <<<dim3(4, 16),     256, 0, stream>>>(UB, WOT, bo, out);
}